// Round 14
// baseline (270.717 us; speedup 1.0000x reference)
//
#include <hip/hip_runtime.h>
#include <hip/hip_bf16.h>

#define HEADS 8
#define D 128
// log2(e) / sqrt(128): q is pre-scaled by this so scores are in exp2 domain.
#define QSCALE 0.12751743f

typedef unsigned short u16;
typedef unsigned int u32;
typedef __attribute__((ext_vector_type(8))) short short8;
typedef __attribute__((ext_vector_type(4))) float f32x4;

static __device__ inline float sbf2f(short s) {
    return __uint_as_float(((u32)(unsigned short)s) << 16);
}
static __device__ inline u16 f2bf(float f) {
    u32 u = __float_as_uint(f);
    return (u16)((u + 0x7FFFu + ((u >> 16) & 1u)) >> 16);
}
static __device__ inline u32 pk2bf(float a, float b) {
    return (u32)f2bf(a) | ((u32)f2bf(b) << 16);
}
// hardware v_cvt_pk_bf16_f32 path
static __device__ inline u32 cvtpk(float a, float b) {
    union { __hip_bfloat162 h; u32 u; } x;
    x.h = __float22bfloat162_rn(make_float2(a, b));
    return x.u;
}
static __device__ inline f32x4 mfma16(short8 a, short8 b, f32x4 c) {
    return __builtin_amdgcn_mfma_f32_16x16x32_bf16(a, b, c, 0, 0, 0);
}
// load 8 consecutive f32 and convert to a bf16 MFMA fragment
static __device__ inline short8 cvt8(const float* e) {
    f32x4 v0 = *(const f32x4*)e;
    f32x4 v1 = *(const f32x4*)(e + 4);
    union { uint4 u; short8 s; } x;
    x.u = make_uint4(pk2bf(v0[0], v0[1]), pk2bf(v0[2], v0[3]),
                     pk2bf(v1[0], v1[1]), pk2bf(v1[2], v1[3]));
    return x.s;
}
// async global->LDS, 16B per lane. Dest = uniform base + lane*16 (HW rule).
static __device__ __forceinline__ void gload_lds16(const void* g, void* l) {
    __builtin_amdgcn_global_load_lds(
        (const __attribute__((address_space(1))) u32*)g,
        (__attribute__((address_space(3))) u32*)(u32)(uintptr_t)l,
        16, 0, 0);
}

// ---------------- K0: convert Wq,Wk,Wv to bf16 ----------------
__global__ __launch_bounds__(256) void k_wcvt(const float* __restrict__ Wq,
    const float* __restrict__ Wk, const float* __restrict__ Wv,
    u16* __restrict__ wqk, u16* __restrict__ wv)
{
    int idx = (blockIdx.x * 256 + threadIdx.x) * 4;   // 393216 floats total
    const float* src;
    u16* dst;
    if (idx < 131072)      { src = Wq + idx;           dst = wqk + idx; }
    else if (idx < 262144) { src = Wk + (idx - 131072); dst = wqk + idx; }
    else                   { src = Wv + (idx - 262144); dst = wv + (idx - 262144); }
    f32x4 v = *(const f32x4*)src;
    *(uint2*)dst = make_uint2(pk2bf(v[0], v[1]), pk2bf(v[2], v[3]));
}

// ---------------- K1: fused LayerNorm + transpose ----------------
__global__ __launch_bounds__(256) void k_lnxt(const float* __restrict__ hs,
    const float* __restrict__ g, const float* __restrict__ bb,
    float* __restrict__ xf, u16* __restrict__ xbf, u16* __restrict__ xt)
{
    __shared__ __align__(16) u16 tl[128][136];
    int b = blockIdx.x, ch = blockIdx.y;
    int tid = threadIdx.x;
    int c4 = (tid & 31) * 4;
    f32x4 g4 = *(const f32x4*)(g + c4);
    f32x4 b4 = *(const f32x4*)(bb + c4);
    const float* src = hs + ((size_t)b * 1024 + ch * 128) * 128;
    #pragma unroll
    for (int it = 0; it < 16; ++it) {
        int p = (tid >> 5) + it * 8;
        f32x4 v = *(const f32x4*)(src + (size_t)p * 128 + c4);
        float s1 = (v[0] + v[1]) + (v[2] + v[3]);
        float s2 = (v[0] * v[0] + v[1] * v[1]) + (v[2] * v[2] + v[3] * v[3]);
        #pragma unroll
        for (int off = 1; off < 32; off <<= 1) {
            s1 += __shfl_xor(s1, off);
            s2 += __shfl_xor(s2, off);
        }
        float mu  = s1 * 0.0078125f;
        float var = s2 * 0.0078125f - mu * mu;
        float inv = rsqrtf(var + 1e-5f);
        f32x4 o;
        #pragma unroll
        for (int q = 0; q < 4; ++q) o[q] = (v[q] - mu) * inv * g4[q] + b4[q];
        size_t row = (size_t)b * 1024 + ch * 128 + p;
        *(f32x4*)(xf + row * 128 + c4) = o;
        *(uint2*)(xbf + row * 128 + c4) = make_uint2(pk2bf(o[0], o[1]), pk2bf(o[2], o[3]));
        tl[c4 + 0][p] = f2bf(o[0]);
        tl[c4 + 1][p] = f2bf(o[1]);
        tl[c4 + 2][p] = f2bf(o[2]);
        tl[c4 + 3][p] = f2bf(o[3]);
    }
    __syncthreads();
    u16* dst = xt + (size_t)b * 131072 + ch * 128;
    #pragma unroll
    for (int i = 0; i < 8; ++i) {
        int d = (tid >> 4) + i * 16, c8 = (tid & 15) * 8;
        *(uint4*)(dst + (size_t)d * 1024 + c8) = *(const uint4*)&tl[d][c8];
    }
}

// ---------------- K2: Q/K projection (MFMA bf16, bf16 weights) ----------------
__global__ __launch_bounds__(256) void k_proj(const u16* __restrict__ xbf,
    const u16* __restrict__ wqk,
    u16* __restrict__ q_bf, u16* __restrict__ kt_bf)
{
    int tid = threadIdx.x;
    int w = tid >> 6, l = tid & 63, h = l >> 4, ln = l & 15;
    int t0 = blockIdx.x * 64 + w * 16;
    int o0 = blockIdx.y * 64;
    short8 a[4];
    #pragma unroll
    for (int s = 0; s < 4; ++s)
        a[s] = *(const short8*)(xbf + (size_t)(t0 + ln) * 128 + s * 32 + h * 8);
    f32x4 acc[4];
    #pragma unroll
    for (int n = 0; n < 4; ++n) acc[n] = f32x4{0.f, 0.f, 0.f, 0.f};
    #pragma unroll
    for (int n = 0; n < 4; ++n) {
        const u16* wsrc = wqk + (size_t)(o0 + n * 16 + ln) * 128;
        #pragma unroll
        for (int s = 0; s < 4; ++s) {
            short8 bf = *(const short8*)(wsrc + s * 32 + h * 8);
            acc[n] = mfma16(a[s], bf, acc[n]);
        }
    }
    bool isq = (o0 < 1024);
    float oscale = isq ? QSCALE : 1.0f;
    int head = (o0 & 1023) >> 7;
    int od_base = (o0 & 127);
    u16* basep = isq ? q_bf : kt_bf;
    #pragma unroll
    for (int n = 0; n < 4; ++n) {
        int d0 = od_base + n * 16 + ln;
        #pragma unroll
        for (int r = 0; r < 4; ++r) {
            int t = t0 + h * 4 + r;
            int b = t >> 10, pos = t & 1023;
            size_t row;
            if (isq) row = (size_t)(b * 8 + head) * 1024 + pos;
            else { int I = pos >> 5, J = pos & 31; row = (size_t)(b * 8 + head) * 1024 + (J * 32 + I); }
            basep[row * 128 + d0] = f2bf(acc[n][r] * oscale);
        }
    }
}

// ---------------- K3: bias GEMMs -> rbias[J][K], cbias[J][L] (pre-gathered) ----
__global__ __launch_bounds__(256) void k_bias(const u16* __restrict__ q_bf,
    const float* __restrict__ row_emb, const float* __restrict__ col_emb,
    float* __restrict__ rbias, float* __restrict__ cbias)
{
    __shared__ __align__(16) float cbf[32][68];
    int tid = threadIdx.x;
    int w = tid >> 6, l = tid & 63, h = l >> 4, ln = l & 15;
    int blk = blockIdx.x;
    int bh = blk >> 5, I = blk & 31;
    const u16* qb = q_bf + ((size_t)bh * 1024 + I * 32) * 128;
    size_t obase = (size_t)blk * 1024;
    if (w < 2) {
        short8 a0 = *(const short8*)(qb + (size_t)(w * 16 + ln) * 128 + h * 8);
        short8 a1 = *(const short8*)(qb + (size_t)(w * 16 + ln) * 128 + 32 + h * 8);
        f32x4 o[2] = {f32x4{0,0,0,0}, f32x4{0,0,0,0}};
        #pragma unroll
        for (int n = 0; n < 2; ++n) {
            int K = n * 16 + ln;
            const float* e = row_emb + (size_t)(K - I + 31) * 64 + h * 8;
            o[n] = mfma16(a0, cvt8(e), o[n]);
            o[n] = mfma16(a1, cvt8(e + 32), o[n]);
        }
        #pragma unroll
        for (int n = 0; n < 2; ++n)
            #pragma unroll
            for (int r = 0; r < 4; ++r)
                rbias[obase + (size_t)(w * 16 + h * 4 + r) * 32 + n * 16 + ln] = o[n][r];
    } else {
        int m = w - 2;
        short8 a0 = *(const short8*)(qb + (size_t)(m * 16 + ln) * 128 + 64 + h * 8);
        short8 a1 = *(const short8*)(qb + (size_t)(m * 16 + ln) * 128 + 96 + h * 8);
        f32x4 o[4] = {f32x4{0,0,0,0}, f32x4{0,0,0,0}, f32x4{0,0,0,0}, f32x4{0,0,0,0}};
        #pragma unroll
        for (int n = 0; n < 4; ++n) {
            int p = n * 16 + ln;
            if (p > 62) p = 62;            // clamp: p=63 never consumed
            const float* e = col_emb + (size_t)p * 64 + h * 8;
            o[n] = mfma16(a0, cvt8(e), o[n]);
            o[n] = mfma16(a1, cvt8(e + 32), o[n]);
        }
        #pragma unroll
        for (int n = 0; n < 4; ++n)
            #pragma unroll
            for (int r = 0; r < 4; ++r)
                cbf[m * 16 + h * 4 + r][n * 16 + ln] = o[n][r];
    }
    __syncthreads();
    int J = tid >> 3, L0 = (tid & 7) * 4;
    float4 g;
    g.x = cbf[J][L0 + 0 - J + 31];
    g.y = cbf[J][L0 + 1 - J + 31];
    g.z = cbf[J][L0 + 2 - J + 31];
    g.w = cbf[J][L0 + 3 - J + 31];
    *(float4*)(cbias + obase + (size_t)J * 32 + L0) = g;
}

// ---------------- K4: fused scores + softmax + PV (async kt + xt prefetch) ----
// 512 threads = 8 waves; block covers I (32 q-rows J), wave w owns kk-span w*128.
// Wave's 8 KB LDS region: streams its 32 KB kt span (8x4KB chunks, dbuf DMA,
// counted vmcnt, per-wave), then holds its P~ slice. XOR involution swizzle on
// both sides (rule #21). No max subtraction (exp2-domain shift-free softmax).
// NEW (R14): xt fragments for PV ks=0..15 prefetched into regs BEFORE a raw
// s_barrier (lgkmcnt(0) only, no vmcnt drain) so the loads fly over the barrier;
// probs drain uses NT stores (256B bursts from LDS-coalesced drain -> no RMW).
__global__ __launch_bounds__(512, 4) void k_attn(const u16* __restrict__ q_bf,
    const u16* __restrict__ kt_bf, const u16* __restrict__ xt_bf,
    const float* __restrict__ rbias, const float* __restrict__ cbias,
    float* __restrict__ probs, u16* __restrict__ ctx_bf)
{
    __shared__ __align__(16) char KT[8 * 8192];   // per-wave 8 KB: kt chunks, then P~
    __shared__ float wred[256];                   // partial sums [w*32 + J]

    int tid = threadIdx.x;
    int w = tid >> 6, l = tid & 63, h = l >> 4, ln = l & 15;
    int flat = blockIdx.x;
    int bh = flat >> 5, I = flat & 31;
    int b = bh >> 3, head = bh & 7;
    int kk0 = w * 128;
    char* reg = KT + w * 8192;
    const char* ktg = (const char*)(kt_bf + ((size_t)bh * 1024 + kk0) * 128);  // 32 KB span
    int d0 = w * 16;
    const u16* xb = xt_bf + (size_t)b * 131072 + (size_t)(d0 + ln) * 1024 + h * 8;

    // ---- prologue VMEM (retire before chunk0 consumed): bias + q ----
    const float* rbase = rbias + (size_t)(bh * 32 + I) * 1024;
    const float* cbase = cbias + (size_t)(bh * 32 + I) * 1024;
    f32x4 rbr[2][2], cbr[2];
    #pragma unroll
    for (int n = 0; n < 2; ++n) {
        int J = n * 16 + ln;
        rbr[n][0] = *(const f32x4*)(rbase + J * 32 + h * 4);
        rbr[n][1] = *(const f32x4*)(rbase + J * 32 + 16 + h * 4);
        cbr[n]    = *(const f32x4*)(cbase + J * 32 + w * 4);
    }
    const u16* qbase = q_bf + ((size_t)bh * 1024 + I * 32) * 128;
    short8 q0[4], q1[4];
    #pragma unroll
    for (int s = 0; s < 4; ++s) {
        q0[s] = *(const short8*)(qbase + (size_t)ln * 128 + s * 32 + h * 8);
        q1[s] = *(const short8*)(qbase + (size_t)(16 + ln) * 128 + s * 32 + h * 8);
    }

    // ---- stage helper: chunk c (16 kk rows, 4 KB) -> buf (0/1), 4 DMA instrs.
    //      source swizzled by involution f(o) = o ^ (((o>>8)&7)<<4). ----
    auto stage_chunk = [&](int c, int buf) {
        const char* gs = ktg + c * 4096;
        char* ld = reg + buf * 4096;
        #pragma unroll
        for (int i = 0; i < 4; ++i) {
            int key = ((i * 4 + (l >> 4)) & 7) << 4;
            int o = i * 1024 + l * 16;
            gload_lds16(gs + (o ^ key), ld + i * 1024);
        }
    };
    stage_chunk(0, 0);
    stage_chunk(1, 1);

    // ---- phase 1: S^T = K Q^T, software-pipelined over 8 chunks ----
    f32x4 acc[2][8];
    #pragma unroll
    for (int n = 0; n < 2; ++n)
        #pragma unroll
        for (int t = 0; t < 8; ++t) acc[n][t] = f32x4{0.f, 0.f, 0.f, 0.f};
    int xk = (ln & 7) << 4;
    #pragma unroll
    for (int c = 0; c < 8; ++c) {
        if (c < 7) asm volatile("s_waitcnt vmcnt(4)" ::: "memory");
        else       asm volatile("s_waitcnt vmcnt(0)" ::: "memory");
        const char* cb = reg + (c & 1) * 4096;
        short8 kf[4];
        #pragma unroll
        for (int s = 0; s < 4; ++s)
            kf[s] = *(const short8*)(cb + ((ln * 256 + s * 64 + h * 16) ^ xk));
        asm volatile("s_waitcnt lgkmcnt(0)" ::: "memory");
        __builtin_amdgcn_sched_barrier(0);
        if (c + 2 < 8) stage_chunk(c + 2, c & 1);
        #pragma unroll
        for (int s = 0; s < 4; ++s) {
            acc[0][c] = mfma16(kf[s], q0[s], acc[0][c]);
            acc[1][c] = mfma16(kf[s], q1[s], acc[1][c]);
        }
    }

    // ---- bias + exp2 + partial row-sum + P~ store into own region ----
    // P~ layout: row J (256 B pitch), kk-local, phys = logical ^ ((J&7)<<4).
    #pragma unroll
    for (int n = 0; n < 2; ++n) {
        int J = n * 16 + ln;
        float sum = 0.f;
        #pragma unroll
        for (int t = 0; t < 8; ++t) {
            float cbv = cbr[n][t >> 1];
            float p0 = exp2f(acc[n][t][0] + rbr[n][t & 1][0] + cbv);
            float p1 = exp2f(acc[n][t][1] + rbr[n][t & 1][1] + cbv);
            float p2 = exp2f(acc[n][t][2] + rbr[n][t & 1][2] + cbv);
            float p3 = exp2f(acc[n][t][3] + rbr[n][t & 1][3] + cbv);
            sum += (p0 + p1) + (p2 + p3);
            *(uint2*)(reg + ((J * 256 + t * 32 + h * 8) ^ xk)) =
                make_uint2(cvtpk(p0, p1), cvtpk(p2, p3));
        }
        sum += __shfl_xor(sum, 16);
        sum += __shfl_xor(sum, 32);
        if (l < 16) wred[w * 32 + J] = sum;
    }

    // ---- xt prefetch for PV ks=0..15, pinned AFTER softmax (acc now dead),
    //      issued BEFORE the barrier so the loads stay in flight across it ----
    __builtin_amdgcn_sched_barrier(0);
    short8 xpre[16];
    #pragma unroll
    for (int ks = 0; ks < 16; ++ks)
        xpre[ks] = *(const short8*)(xb + ks * 32);
    // raw barrier: LDS visibility needs lgkmcnt(0) only; do NOT drain vmcnt
    asm volatile("s_waitcnt lgkmcnt(0)" ::: "memory");
    __builtin_amdgcn_s_barrier();

    // ---- per-thread row sums (broadcast f32x4 LDS reads) ----
    f32x4 sum0 = f32x4{0.f, 0.f, 0.f, 0.f};
    f32x4 sum1 = f32x4{0.f, 0.f, 0.f, 0.f};
    #pragma unroll
    for (int w2 = 0; w2 < 8; ++w2) {
        sum0 += *(const f32x4*)&wred[w2 * 32 + h * 4];
        sum1 += *(const f32x4*)&wred[w2 * 32 + 16 + h * 4];
    }
    int j = tid >> 4;
    float sd = 0.f;
    #pragma unroll
    for (int w2 = 0; w2 < 8; ++w2) sd += wred[w2 * 32 + j];
    float invd = 1.0f / sd;

    // ---- probs drain from LDS, coalesced (16 lanes sweep one J row; 256B
    //      bursts), NT stores (write-once data; full sectors -> no RMW),
    //      before PV so stores retire under the MFMA phase ----
    {
        float* prow = probs + ((((size_t)(b * 32 + j) * 32 + I) * 8 + head) << 10);
        int jx = (j & 7) << 4;
        #pragma unroll
        for (int i = 0; i < 8; ++i) {
            int kk = i * 128 + (tid & 15) * 8;
            short8 pv = *(const short8*)(KT + i * 8192 +
                            ((j * 256 + (tid & 15) * 16) ^ jx));
            f32x4 o0, o1;
            o0[0] = sbf2f(pv[0]) * invd; o0[1] = sbf2f(pv[1]) * invd;
            o0[2] = sbf2f(pv[2]) * invd; o0[3] = sbf2f(pv[3]) * invd;
            o1[0] = sbf2f(pv[4]) * invd; o1[1] = sbf2f(pv[5]) * invd;
            o1[2] = sbf2f(pv[6]) * invd; o1[3] = sbf2f(pv[7]) * invd;
            __builtin_nontemporal_store(o0, (f32x4*)(prow + kk));
            __builtin_nontemporal_store(o1, (f32x4*)(prow + kk + 4));
        }
    }

    // ---- PV: ctx = P~ @ X  (wave w -> d-span w*16) ----
    f32x4 cacc[2] = {f32x4{0,0,0,0}, f32x4{0,0,0,0}};
    #pragma unroll
    for (int ks = 0; ks < 32; ++ks) {
        short8 xf8 = (ks < 16) ? xpre[ks] : *(const short8*)(xb + ks * 32);
        #pragma unroll
        for (int m = 0; m < 2; ++m) {
            short8 pa = *(const short8*)(KT + (ks >> 2) * 8192 +
                (((m * 16 + ln) * 256 + (ks & 3) * 64 + h * 16) ^ xk));
            cacc[m] = mfma16(pa, xf8, cacc[m]);
        }
    }
    #pragma unroll
    for (int m = 0; m < 2; ++m)
        #pragma unroll
        for (int r = 0; r < 4; ++r) {
            int J = m * 16 + h * 4 + r;
            float inv = 1.0f / (m ? sum1[r] : sum0[r]);
            ctx_bf[((size_t)(b * 32 + J) * 32 + I) * 1024 + head * 128 + d0 + ln] =
                f2bf(cacc[m][r] * inv);
        }
}

// ---------------- K7: output = ctx @ Wv^T + bv + x (MFMA) ----------------
__global__ __launch_bounds__(256) void k_out(const u16* __restrict__ ctx_bf,
    const u16* __restrict__ wv_bf, const float* __restrict__ bv,
    const float* __restrict__ xf, float* __restrict__ out)
{
    int tid = threadIdx.x;
    int w = tid >> 6, l = tid & 63, h = l >> 4, ln = l & 15;
    int wm = w >> 1, wn = w & 1;
    int t0 = blockIdx.x * 32 + wm * 16;
    int o0 = blockIdx.y * 64 + wn * 32;
    f32x4 acc[2] = {f32x4{0,0,0,0}, f32x4{0,0,0,0}};
    for (int ks = 0; ks < 32; ++ks) {
        short8 a = *(const short8*)(ctx_bf + (size_t)(t0 + ln) * 1024 + ks * 32 + h * 8);
        #pragma unroll
        for (int nt = 0; nt < 2; ++nt) {
            short8 bb = *(const short8*)(wv_bf + (size_t)(o0 + nt * 16 + ln) * 1024 + ks * 32 + h * 8);
            acc[nt] = mfma16(a, bb, acc[nt]);
        }
    }
    #pragma unroll
    for (int nt = 0; nt < 2; ++nt) {
        int o = o0 + nt * 16 + ln;
        float bvv = bv[o];
        #pragma unroll
        for (int r = 0; r < 4; ++r) {
            int t = t0 + h * 4 + r;
            out[(size_t)t * 128 + o] = acc[nt][r] + bvv + xf[(size_t)t * 128 + o];
        }
    }
}

extern "C" void kernel_launch(void* const* d_in, const int* in_sizes, int n_in,
                              void* d_out, int out_size, void* d_ws, size_t ws_size,
                              hipStream_t stream) {
    (void)in_sizes; (void)n_in; (void)out_size; (void)ws_size;
    const float* hs      = (const float*)d_in[0];
    const float* row_emb = (const float*)d_in[1];
    const float* col_emb = (const float*)d_in[2];
    const float* Wq      = (const float*)d_in[3];
    const float* Wk      = (const float*)d_in[4];
    const float* Wv      = (const float*)d_in[5];
    const float* bv      = (const float*)d_in[6];
    const float* ln_g    = (const float*)d_in[7];
    const float* ln_b    = (const float*)d_in[8];

    float* out   = (float*)d_out;
    float* probs = out + 1048576;

    char* ws = (char*)d_ws;
    float* xf     = (float*)(ws);                      //  4 MB
    u16*   xbf    = (u16*)(ws + 4194304);              //  2 MB
    u16*   q_bf   = (u16*)(ws + 6291456);              // 16 MB
    u16*   kt_bf  = (u16*)(ws + 23068672);             // 16 MB
    u16*   xt     = (u16*)(ws + 39845888);             //  2 MB
    u16*   wqk_bf = (u16*)(ws + 41943040);             // 512 KB
    u16*   wv_bf  = (u16*)(ws + 42467328);             // 256 KB
    u16*   ctx    = (u16*)(ws + 42729472);             // 16 MB
    float* rbias  = (float*)(ws + 59506688);           //  8 MB
    float* cbias  = (float*)(ws + 67895296);           //  8 MB  (total 72.75 MB)

    k_wcvt <<<384, 256, 0, stream>>>(Wq, Wk, Wv, wqk_bf, wv_bf);
    k_lnxt <<<dim3(8, 8), 256, 0, stream>>>(hs, ln_g, ln_b, xf, xbf, xt);
    k_proj <<<dim3(128, 32), 256, 0, stream>>>(xbf, wqk_bf, q_bf, kt_bf);
    k_bias <<<2048, 256, 0, stream>>>(q_bf, row_emb, col_emb, rbias, cbias);
    k_attn <<<2048, 512, 0, stream>>>(q_bf, kt_bf, xt, rbias, cbias, probs, ctx);
    k_out  <<<dim3(256, 2), 256, 0, stream>>>(ctx, wv_bf, bv, xf, out);
}

// Round 15
// 255.719 us; speedup vs baseline: 1.0587x; 1.0587x over previous
//
#include <hip/hip_runtime.h>
#include <hip/hip_bf16.h>

#define HEADS 8
#define D 128
// log2(e) / sqrt(128): q is pre-scaled by this so scores are in exp2 domain.
#define QSCALE 0.12751743f

typedef unsigned short u16;
typedef unsigned int u32;
typedef __attribute__((ext_vector_type(8))) short short8;
typedef __attribute__((ext_vector_type(4))) float f32x4;

static __device__ inline float sbf2f(short s) {
    return __uint_as_float(((u32)(unsigned short)s) << 16);
}
static __device__ inline u16 f2bf(float f) {
    u32 u = __float_as_uint(f);
    return (u16)((u + 0x7FFFu + ((u >> 16) & 1u)) >> 16);
}
static __device__ inline u32 pk2bf(float a, float b) {
    return (u32)f2bf(a) | ((u32)f2bf(b) << 16);
}
// hardware v_cvt_pk_bf16_f32 path
static __device__ inline u32 cvtpk(float a, float b) {
    union { __hip_bfloat162 h; u32 u; } x;
    x.h = __float22bfloat162_rn(make_float2(a, b));
    return x.u;
}
static __device__ inline f32x4 mfma16(short8 a, short8 b, f32x4 c) {
    return __builtin_amdgcn_mfma_f32_16x16x32_bf16(a, b, c, 0, 0, 0);
}
// load 8 consecutive f32 and convert to a bf16 MFMA fragment
static __device__ inline short8 cvt8(const float* e) {
    f32x4 v0 = *(const f32x4*)e;
    f32x4 v1 = *(const f32x4*)(e + 4);
    union { uint4 u; short8 s; } x;
    x.u = make_uint4(pk2bf(v0[0], v0[1]), pk2bf(v0[2], v0[3]),
                     pk2bf(v1[0], v1[1]), pk2bf(v1[2], v1[3]));
    return x.s;
}
// async global->LDS, 16B per lane. Dest = uniform base + lane*16 (HW rule).
static __device__ __forceinline__ void gload_lds16(const void* g, void* l) {
    __builtin_amdgcn_global_load_lds(
        (const __attribute__((address_space(1))) u32*)g,
        (__attribute__((address_space(3))) u32*)(u32)(uintptr_t)l,
        16, 0, 0);
}

// ---------------- K0: convert Wq,Wk,Wv to bf16 ----------------
__global__ __launch_bounds__(256) void k_wcvt(const float* __restrict__ Wq,
    const float* __restrict__ Wk, const float* __restrict__ Wv,
    u16* __restrict__ wqk, u16* __restrict__ wv)
{
    int idx = (blockIdx.x * 256 + threadIdx.x) * 4;   // 393216 floats total
    const float* src;
    u16* dst;
    if (idx < 131072)      { src = Wq + idx;           dst = wqk + idx; }
    else if (idx < 262144) { src = Wk + (idx - 131072); dst = wqk + idx; }
    else                   { src = Wv + (idx - 262144); dst = wv + (idx - 262144); }
    f32x4 v = *(const f32x4*)src;
    *(uint2*)dst = make_uint2(pk2bf(v[0], v[1]), pk2bf(v[2], v[3]));
}

// ---------------- K1: fused LayerNorm + transpose ----------------
__global__ __launch_bounds__(256) void k_lnxt(const float* __restrict__ hs,
    const float* __restrict__ g, const float* __restrict__ bb,
    float* __restrict__ xf, u16* __restrict__ xbf, u16* __restrict__ xt)
{
    __shared__ __align__(16) u16 tl[128][136];
    int b = blockIdx.x, ch = blockIdx.y;
    int tid = threadIdx.x;
    int c4 = (tid & 31) * 4;
    f32x4 g4 = *(const f32x4*)(g + c4);
    f32x4 b4 = *(const f32x4*)(bb + c4);
    const float* src = hs + ((size_t)b * 1024 + ch * 128) * 128;
    #pragma unroll
    for (int it = 0; it < 16; ++it) {
        int p = (tid >> 5) + it * 8;
        f32x4 v = *(const f32x4*)(src + (size_t)p * 128 + c4);
        float s1 = (v[0] + v[1]) + (v[2] + v[3]);
        float s2 = (v[0] * v[0] + v[1] * v[1]) + (v[2] * v[2] + v[3] * v[3]);
        #pragma unroll
        for (int off = 1; off < 32; off <<= 1) {
            s1 += __shfl_xor(s1, off);
            s2 += __shfl_xor(s2, off);
        }
        float mu  = s1 * 0.0078125f;
        float var = s2 * 0.0078125f - mu * mu;
        float inv = rsqrtf(var + 1e-5f);
        f32x4 o;
        #pragma unroll
        for (int q = 0; q < 4; ++q) o[q] = (v[q] - mu) * inv * g4[q] + b4[q];
        size_t row = (size_t)b * 1024 + ch * 128 + p;
        *(f32x4*)(xf + row * 128 + c4) = o;
        *(uint2*)(xbf + row * 128 + c4) = make_uint2(pk2bf(o[0], o[1]), pk2bf(o[2], o[3]));
        tl[c4 + 0][p] = f2bf(o[0]);
        tl[c4 + 1][p] = f2bf(o[1]);
        tl[c4 + 2][p] = f2bf(o[2]);
        tl[c4 + 3][p] = f2bf(o[3]);
    }
    __syncthreads();
    u16* dst = xt + (size_t)b * 131072 + ch * 128;
    #pragma unroll
    for (int i = 0; i < 8; ++i) {
        int d = (tid >> 4) + i * 16, c8 = (tid & 15) * 8;
        *(uint4*)(dst + (size_t)d * 1024 + c8) = *(const uint4*)&tl[d][c8];
    }
}

// ---------------- K2: Q/K projection (MFMA bf16, bf16 weights) ----------------
__global__ __launch_bounds__(256) void k_proj(const u16* __restrict__ xbf,
    const u16* __restrict__ wqk,
    u16* __restrict__ q_bf, u16* __restrict__ kt_bf)
{
    int tid = threadIdx.x;
    int w = tid >> 6, l = tid & 63, h = l >> 4, ln = l & 15;
    int t0 = blockIdx.x * 64 + w * 16;
    int o0 = blockIdx.y * 64;
    short8 a[4];
    #pragma unroll
    for (int s = 0; s < 4; ++s)
        a[s] = *(const short8*)(xbf + (size_t)(t0 + ln) * 128 + s * 32 + h * 8);
    f32x4 acc[4];
    #pragma unroll
    for (int n = 0; n < 4; ++n) acc[n] = f32x4{0.f, 0.f, 0.f, 0.f};
    #pragma unroll
    for (int n = 0; n < 4; ++n) {
        const u16* wsrc = wqk + (size_t)(o0 + n * 16 + ln) * 128;
        #pragma unroll
        for (int s = 0; s < 4; ++s) {
            short8 bf = *(const short8*)(wsrc + s * 32 + h * 8);
            acc[n] = mfma16(a[s], bf, acc[n]);
        }
    }
    bool isq = (o0 < 1024);
    float oscale = isq ? QSCALE : 1.0f;
    int head = (o0 & 1023) >> 7;
    int od_base = (o0 & 127);
    u16* basep = isq ? q_bf : kt_bf;
    #pragma unroll
    for (int n = 0; n < 4; ++n) {
        int d0 = od_base + n * 16 + ln;
        #pragma unroll
        for (int r = 0; r < 4; ++r) {
            int t = t0 + h * 4 + r;
            int b = t >> 10, pos = t & 1023;
            size_t row;
            if (isq) row = (size_t)(b * 8 + head) * 1024 + pos;
            else { int I = pos >> 5, J = pos & 31; row = (size_t)(b * 8 + head) * 1024 + (J * 32 + I); }
            basep[row * 128 + d0] = f2bf(acc[n][r] * oscale);
        }
    }
}

// ---------------- K3: bias GEMMs -> rbias[J][K], cbias[J][L] (pre-gathered) ----
__global__ __launch_bounds__(256) void k_bias(const u16* __restrict__ q_bf,
    const float* __restrict__ row_emb, const float* __restrict__ col_emb,
    float* __restrict__ rbias, float* __restrict__ cbias)
{
    __shared__ __align__(16) float cbf[32][68];
    int tid = threadIdx.x;
    int w = tid >> 6, l = tid & 63, h = l >> 4, ln = l & 15;
    int blk = blockIdx.x;
    int bh = blk >> 5, I = blk & 31;
    const u16* qb = q_bf + ((size_t)bh * 1024 + I * 32) * 128;
    size_t obase = (size_t)blk * 1024;
    if (w < 2) {
        short8 a0 = *(const short8*)(qb + (size_t)(w * 16 + ln) * 128 + h * 8);
        short8 a1 = *(const short8*)(qb + (size_t)(w * 16 + ln) * 128 + 32 + h * 8);
        f32x4 o[2] = {f32x4{0,0,0,0}, f32x4{0,0,0,0}};
        #pragma unroll
        for (int n = 0; n < 2; ++n) {
            int K = n * 16 + ln;
            const float* e = row_emb + (size_t)(K - I + 31) * 64 + h * 8;
            o[n] = mfma16(a0, cvt8(e), o[n]);
            o[n] = mfma16(a1, cvt8(e + 32), o[n]);
        }
        #pragma unroll
        for (int n = 0; n < 2; ++n)
            #pragma unroll
            for (int r = 0; r < 4; ++r)
                rbias[obase + (size_t)(w * 16 + h * 4 + r) * 32 + n * 16 + ln] = o[n][r];
    } else {
        int m = w - 2;
        short8 a0 = *(const short8*)(qb + (size_t)(m * 16 + ln) * 128 + 64 + h * 8);
        short8 a1 = *(const short8*)(qb + (size_t)(m * 16 + ln) * 128 + 96 + h * 8);
        f32x4 o[4] = {f32x4{0,0,0,0}, f32x4{0,0,0,0}, f32x4{0,0,0,0}, f32x4{0,0,0,0}};
        #pragma unroll
        for (int n = 0; n < 4; ++n) {
            int p = n * 16 + ln;
            if (p > 62) p = 62;            // clamp: p=63 never consumed
            const float* e = col_emb + (size_t)p * 64 + h * 8;
            o[n] = mfma16(a0, cvt8(e), o[n]);
            o[n] = mfma16(a1, cvt8(e + 32), o[n]);
        }
        #pragma unroll
        for (int n = 0; n < 4; ++n)
            #pragma unroll
            for (int r = 0; r < 4; ++r)
                cbf[m * 16 + h * 4 + r][n * 16 + ln] = o[n][r];
    }
    __syncthreads();
    int J = tid >> 3, L0 = (tid & 7) * 4;
    float4 g;
    g.x = cbf[J][L0 + 0 - J + 31];
    g.y = cbf[J][L0 + 1 - J + 31];
    g.z = cbf[J][L0 + 2 - J + 31];
    g.w = cbf[J][L0 + 3 - J + 31];
    *(float4*)(cbias + obase + (size_t)J * 32 + L0) = g;
}

// ---------------- K4: fused scores + softmax + PV (async kt + xt prefetch) ----
// R15 = R13 + xt-prefetch-over-raw-barrier, NT stores REVERTED (NT needs a
// single instruction to cover whole 64B sectors; 16B-max stores can't -> RMW,
// +158MB WRITE measured in R14).
__global__ __launch_bounds__(512, 4) void k_attn(const u16* __restrict__ q_bf,
    const u16* __restrict__ kt_bf, const u16* __restrict__ xt_bf,
    const float* __restrict__ rbias, const float* __restrict__ cbias,
    float* __restrict__ probs, u16* __restrict__ ctx_bf)
{
    __shared__ __align__(16) char KT[8 * 8192];   // per-wave 8 KB: kt chunks, then P~
    __shared__ float wred[256];                   // partial sums [w*32 + J]

    int tid = threadIdx.x;
    int w = tid >> 6, l = tid & 63, h = l >> 4, ln = l & 15;
    int flat = blockIdx.x;
    int bh = flat >> 5, I = flat & 31;
    int b = bh >> 3, head = bh & 7;
    int kk0 = w * 128;
    char* reg = KT + w * 8192;
    const char* ktg = (const char*)(kt_bf + ((size_t)bh * 1024 + kk0) * 128);  // 32 KB span
    int d0 = w * 16;
    const u16* xb = xt_bf + (size_t)b * 131072 + (size_t)(d0 + ln) * 1024 + h * 8;

    // ---- prologue VMEM (retire before chunk0 consumed): bias + q ----
    const float* rbase = rbias + (size_t)(bh * 32 + I) * 1024;
    const float* cbase = cbias + (size_t)(bh * 32 + I) * 1024;
    f32x4 rbr[2][2], cbr[2];
    #pragma unroll
    for (int n = 0; n < 2; ++n) {
        int J = n * 16 + ln;
        rbr[n][0] = *(const f32x4*)(rbase + J * 32 + h * 4);
        rbr[n][1] = *(const f32x4*)(rbase + J * 32 + 16 + h * 4);
        cbr[n]    = *(const f32x4*)(cbase + J * 32 + w * 4);
    }
    const u16* qbase = q_bf + ((size_t)bh * 1024 + I * 32) * 128;
    short8 q0[4], q1[4];
    #pragma unroll
    for (int s = 0; s < 4; ++s) {
        q0[s] = *(const short8*)(qbase + (size_t)ln * 128 + s * 32 + h * 8);
        q1[s] = *(const short8*)(qbase + (size_t)(16 + ln) * 128 + s * 32 + h * 8);
    }

    // ---- stage helper: chunk c (16 kk rows, 4 KB) -> buf (0/1), 4 DMA instrs.
    //      source swizzled by involution f(o) = o ^ (((o>>8)&7)<<4). ----
    auto stage_chunk = [&](int c, int buf) {
        const char* gs = ktg + c * 4096;
        char* ld = reg + buf * 4096;
        #pragma unroll
        for (int i = 0; i < 4; ++i) {
            int key = ((i * 4 + (l >> 4)) & 7) << 4;
            int o = i * 1024 + l * 16;
            gload_lds16(gs + (o ^ key), ld + i * 1024);
        }
    };
    stage_chunk(0, 0);
    stage_chunk(1, 1);

    // ---- phase 1: S^T = K Q^T, software-pipelined over 8 chunks ----
    f32x4 acc[2][8];
    #pragma unroll
    for (int n = 0; n < 2; ++n)
        #pragma unroll
        for (int t = 0; t < 8; ++t) acc[n][t] = f32x4{0.f, 0.f, 0.f, 0.f};
    int xk = (ln & 7) << 4;
    #pragma unroll
    for (int c = 0; c < 8; ++c) {
        if (c < 7) asm volatile("s_waitcnt vmcnt(4)" ::: "memory");
        else       asm volatile("s_waitcnt vmcnt(0)" ::: "memory");
        const char* cb = reg + (c & 1) * 4096;
        short8 kf[4];
        #pragma unroll
        for (int s = 0; s < 4; ++s)
            kf[s] = *(const short8*)(cb + ((ln * 256 + s * 64 + h * 16) ^ xk));
        asm volatile("s_waitcnt lgkmcnt(0)" ::: "memory");
        __builtin_amdgcn_sched_barrier(0);
        if (c + 2 < 8) stage_chunk(c + 2, c & 1);
        #pragma unroll
        for (int s = 0; s < 4; ++s) {
            acc[0][c] = mfma16(kf[s], q0[s], acc[0][c]);
            acc[1][c] = mfma16(kf[s], q1[s], acc[1][c]);
        }
    }

    // ---- bias + exp2 + partial row-sum + P~ store into own region ----
    // P~ layout: row J (256 B pitch), kk-local, phys = logical ^ ((J&7)<<4).
    #pragma unroll
    for (int n = 0; n < 2; ++n) {
        int J = n * 16 + ln;
        float sum = 0.f;
        #pragma unroll
        for (int t = 0; t < 8; ++t) {
            float cbv = cbr[n][t >> 1];
            float p0 = exp2f(acc[n][t][0] + rbr[n][t & 1][0] + cbv);
            float p1 = exp2f(acc[n][t][1] + rbr[n][t & 1][1] + cbv);
            float p2 = exp2f(acc[n][t][2] + rbr[n][t & 1][2] + cbv);
            float p3 = exp2f(acc[n][t][3] + rbr[n][t & 1][3] + cbv);
            sum += (p0 + p1) + (p2 + p3);
            *(uint2*)(reg + ((J * 256 + t * 32 + h * 8) ^ xk)) =
                make_uint2(cvtpk(p0, p1), cvtpk(p2, p3));
        }
        sum += __shfl_xor(sum, 16);
        sum += __shfl_xor(sum, 32);
        if (l < 16) wred[w * 32 + J] = sum;
    }

    // ---- xt prefetch for PV ks=0..15, pinned AFTER softmax (acc now dead),
    //      issued BEFORE the barrier so the loads stay in flight across it ----
    __builtin_amdgcn_sched_barrier(0);
    short8 xpre[16];
    #pragma unroll
    for (int ks = 0; ks < 16; ++ks)
        xpre[ks] = *(const short8*)(xb + ks * 32);
    // raw barrier: LDS visibility needs lgkmcnt(0) only; do NOT drain vmcnt
    asm volatile("s_waitcnt lgkmcnt(0)" ::: "memory");
    __builtin_amdgcn_s_barrier();

    // ---- per-thread row sums (broadcast f32x4 LDS reads) ----
    f32x4 sum0 = f32x4{0.f, 0.f, 0.f, 0.f};
    f32x4 sum1 = f32x4{0.f, 0.f, 0.f, 0.f};
    #pragma unroll
    for (int w2 = 0; w2 < 8; ++w2) {
        sum0 += *(const f32x4*)&wred[w2 * 32 + h * 4];
        sum1 += *(const f32x4*)&wred[w2 * 32 + 16 + h * 4];
    }
    int j = tid >> 4;
    float sd = 0.f;
    #pragma unroll
    for (int w2 = 0; w2 < 8; ++w2) sd += wred[w2 * 32 + j];
    float invd = 1.0f / sd;

    // ---- probs drain from LDS, coalesced (16 lanes sweep one J row; 512B
    //      per i across the quarter-wave), PLAIN stores (L2 merges halves),
    //      before PV so stores retire under the MFMA phase ----
    {
        float* prow = probs + ((((size_t)(b * 32 + j) * 32 + I) * 8 + head) << 10);
        int jx = (j & 7) << 4;
        #pragma unroll
        for (int i = 0; i < 8; ++i) {
            int kk = i * 128 + (tid & 15) * 8;
            short8 pv = *(const short8*)(KT + i * 8192 +
                            ((j * 256 + (tid & 15) * 16) ^ jx));
            float4 o0, o1;
            o0.x = sbf2f(pv[0]) * invd; o0.y = sbf2f(pv[1]) * invd;
            o0.z = sbf2f(pv[2]) * invd; o0.w = sbf2f(pv[3]) * invd;
            o1.x = sbf2f(pv[4]) * invd; o1.y = sbf2f(pv[5]) * invd;
            o1.z = sbf2f(pv[6]) * invd; o1.w = sbf2f(pv[7]) * invd;
            *(float4*)(prow + kk)     = o0;
            *(float4*)(prow + kk + 4) = o1;
        }
    }

    // ---- PV: ctx = P~ @ X  (wave w -> d-span w*16) ----
    f32x4 cacc[2] = {f32x4{0,0,0,0}, f32x4{0,0,0,0}};
    #pragma unroll
    for (int ks = 0; ks < 32; ++ks) {
        short8 xf8 = (ks < 16) ? xpre[ks] : *(const short8*)(xb + ks * 32);
        #pragma unroll
        for (int m = 0; m < 2; ++m) {
            short8 pa = *(const short8*)(KT + (ks >> 2) * 8192 +
                (((m * 16 + ln) * 256 + (ks & 3) * 64 + h * 16) ^ xk));
            cacc[m] = mfma16(pa, xf8, cacc[m]);
        }
    }
    #pragma unroll
    for (int m = 0; m < 2; ++m)
        #pragma unroll
        for (int r = 0; r < 4; ++r) {
            int J = m * 16 + h * 4 + r;
            float inv = 1.0f / (m ? sum1[r] : sum0[r]);
            ctx_bf[((size_t)(b * 32 + J) * 32 + I) * 1024 + head * 128 + d0 + ln] =
                f2bf(cacc[m][r] * inv);
        }
}

// ---------------- K7: output = ctx @ Wv^T + bv + x (MFMA) ----------------
__global__ __launch_bounds__(256) void k_out(const u16* __restrict__ ctx_bf,
    const u16* __restrict__ wv_bf, const float* __restrict__ bv,
    const float* __restrict__ xf, float* __restrict__ out)
{
    int tid = threadIdx.x;
    int w = tid >> 6, l = tid & 63, h = l >> 4, ln = l & 15;
    int wm = w >> 1, wn = w & 1;
    int t0 = blockIdx.x * 32 + wm * 16;
    int o0 = blockIdx.y * 64 + wn * 32;
    f32x4 acc[2] = {f32x4{0,0,0,0}, f32x4{0,0,0,0}};
    for (int ks = 0; ks < 32; ++ks) {
        short8 a = *(const short8*)(ctx_bf + (size_t)(t0 + ln) * 1024 + ks * 32 + h * 8);
        #pragma unroll
        for (int nt = 0; nt < 2; ++nt) {
            short8 bb = *(const short8*)(wv_bf + (size_t)(o0 + nt * 16 + ln) * 1024 + ks * 32 + h * 8);
            acc[nt] = mfma16(a, bb, acc[nt]);
        }
    }
    #pragma unroll
    for (int nt = 0; nt < 2; ++nt) {
        int o = o0 + nt * 16 + ln;
        float bvv = bv[o];
        #pragma unroll
        for (int r = 0; r < 4; ++r) {
            int t = t0 + h * 4 + r;
            out[(size_t)t * 128 + o] = acc[nt][r] + bvv + xf[(size_t)t * 128 + o];
        }
    }
}

extern "C" void kernel_launch(void* const* d_in, const int* in_sizes, int n_in,
                              void* d_out, int out_size, void* d_ws, size_t ws_size,
                              hipStream_t stream) {
    (void)in_sizes; (void)n_in; (void)out_size; (void)ws_size;
    const float* hs      = (const float*)d_in[0];
    const float* row_emb = (const float*)d_in[1];
    const float* col_emb = (const float*)d_in[2];
    const float* Wq      = (const float*)d_in[3];
    const float* Wk      = (const float*)d_in[4];
    const float* Wv      = (const float*)d_in[5];
    const float* bv      = (const float*)d_in[6];
    const float* ln_g    = (const float*)d_in[7];
    const float* ln_b    = (const float*)d_in[8];

    float* out   = (float*)d_out;
    float* probs = out + 1048576;

    char* ws = (char*)d_ws;
    float* xf     = (float*)(ws);                      //  4 MB
    u16*   xbf    = (u16*)(ws + 4194304);              //  2 MB
    u16*   q_bf   = (u16*)(ws + 6291456);              // 16 MB
    u16*   kt_bf  = (u16*)(ws + 23068672);             // 16 MB
    u16*   xt     = (u16*)(ws + 39845888);             //  2 MB
    u16*   wqk_bf = (u16*)(ws + 41943040);             // 512 KB
    u16*   wv_bf  = (u16*)(ws + 42467328);             // 256 KB
    u16*   ctx    = (u16*)(ws + 42729472);             // 16 MB
    float* rbias  = (float*)(ws + 59506688);           //  8 MB
    float* cbias  = (float*)(ws + 67895296);           //  8 MB  (total 72.75 MB)

    k_wcvt <<<384, 256, 0, stream>>>(Wq, Wk, Wv, wqk_bf, wv_bf);
    k_lnxt <<<dim3(8, 8), 256, 0, stream>>>(hs, ln_g, ln_b, xf, xbf, xt);
    k_proj <<<dim3(128, 32), 256, 0, stream>>>(xbf, wqk_bf, q_bf, kt_bf);
    k_bias <<<2048, 256, 0, stream>>>(q_bf, row_emb, col_emb, rbias, cbias);
    k_attn <<<2048, 512, 0, stream>>>(q_bf, kt_bf, xt, rbias, cbias, probs, ctx);
    k_out  <<<dim3(256, 2), 256, 0, stream>>>(ctx, wv_bf, bv, xf, out);
}

// Round 16
// 251.518 us; speedup vs baseline: 1.0763x; 1.0167x over previous
//
#include <hip/hip_runtime.h>
#include <hip/hip_bf16.h>

#define HEADS 8
#define D 128
// log2(e) / sqrt(128): q is pre-scaled by this so scores are in exp2 domain.
#define QSCALE 0.12751743f

typedef unsigned short u16;
typedef unsigned int u32;
typedef __attribute__((ext_vector_type(8))) short short8;
typedef __attribute__((ext_vector_type(4))) float f32x4;

static __device__ inline float sbf2f(short s) {
    return __uint_as_float(((u32)(unsigned short)s) << 16);
}
static __device__ inline u16 f2bf(float f) {
    u32 u = __float_as_uint(f);
    return (u16)((u + 0x7FFFu + ((u >> 16) & 1u)) >> 16);
}
static __device__ inline u32 pk2bf(float a, float b) {
    return (u32)f2bf(a) | ((u32)f2bf(b) << 16);
}
// hardware v_cvt_pk_bf16_f32 path
static __device__ inline u32 cvtpk(float a, float b) {
    union { __hip_bfloat162 h; u32 u; } x;
    x.h = __float22bfloat162_rn(make_float2(a, b));
    return x.u;
}
static __device__ inline f32x4 mfma16(short8 a, short8 b, f32x4 c) {
    return __builtin_amdgcn_mfma_f32_16x16x32_bf16(a, b, c, 0, 0, 0);
}
// load 8 consecutive f32 and convert to a bf16 MFMA fragment
static __device__ inline short8 cvt8(const float* e) {
    f32x4 v0 = *(const f32x4*)e;
    f32x4 v1 = *(const f32x4*)(e + 4);
    union { uint4 u; short8 s; } x;
    x.u = make_uint4(pk2bf(v0[0], v0[1]), pk2bf(v0[2], v0[3]),
                     pk2bf(v1[0], v1[1]), pk2bf(v1[2], v1[3]));
    return x.s;
}
// async global->LDS, 16B per lane. Dest = uniform base + lane*16 (HW rule).
static __device__ __forceinline__ void gload_lds16(const void* g, void* l) {
    __builtin_amdgcn_global_load_lds(
        (const __attribute__((address_space(1))) u32*)g,
        (__attribute__((address_space(3))) u32*)(u32)(uintptr_t)l,
        16, 0, 0);
}

// ---------------- K0: convert Wq,Wk,Wv to bf16 ----------------
__global__ __launch_bounds__(256) void k_wcvt(const float* __restrict__ Wq,
    const float* __restrict__ Wk, const float* __restrict__ Wv,
    u16* __restrict__ wqk, u16* __restrict__ wv)
{
    int idx = (blockIdx.x * 256 + threadIdx.x) * 4;   // 393216 floats total
    const float* src;
    u16* dst;
    if (idx < 131072)      { src = Wq + idx;           dst = wqk + idx; }
    else if (idx < 262144) { src = Wk + (idx - 131072); dst = wqk + idx; }
    else                   { src = Wv + (idx - 262144); dst = wv + (idx - 262144); }
    f32x4 v = *(const f32x4*)src;
    *(uint2*)dst = make_uint2(pk2bf(v[0], v[1]), pk2bf(v[2], v[3]));
}

// ---------------- K1: fused LayerNorm + transpose ----------------
__global__ __launch_bounds__(256) void k_lnxt(const float* __restrict__ hs,
    const float* __restrict__ g, const float* __restrict__ bb,
    float* __restrict__ xf, u16* __restrict__ xbf, u16* __restrict__ xt)
{
    __shared__ __align__(16) u16 tl[128][136];
    int b = blockIdx.x, ch = blockIdx.y;
    int tid = threadIdx.x;
    int c4 = (tid & 31) * 4;
    f32x4 g4 = *(const f32x4*)(g + c4);
    f32x4 b4 = *(const f32x4*)(bb + c4);
    const float* src = hs + ((size_t)b * 1024 + ch * 128) * 128;
    #pragma unroll
    for (int it = 0; it < 16; ++it) {
        int p = (tid >> 5) + it * 8;
        f32x4 v = *(const f32x4*)(src + (size_t)p * 128 + c4);
        float s1 = (v[0] + v[1]) + (v[2] + v[3]);
        float s2 = (v[0] * v[0] + v[1] * v[1]) + (v[2] * v[2] + v[3] * v[3]);
        #pragma unroll
        for (int off = 1; off < 32; off <<= 1) {
            s1 += __shfl_xor(s1, off);
            s2 += __shfl_xor(s2, off);
        }
        float mu  = s1 * 0.0078125f;
        float var = s2 * 0.0078125f - mu * mu;
        float inv = rsqrtf(var + 1e-5f);
        f32x4 o;
        #pragma unroll
        for (int q = 0; q < 4; ++q) o[q] = (v[q] - mu) * inv * g4[q] + b4[q];
        size_t row = (size_t)b * 1024 + ch * 128 + p;
        *(f32x4*)(xf + row * 128 + c4) = o;
        *(uint2*)(xbf + row * 128 + c4) = make_uint2(pk2bf(o[0], o[1]), pk2bf(o[2], o[3]));
        tl[c4 + 0][p] = f2bf(o[0]);
        tl[c4 + 1][p] = f2bf(o[1]);
        tl[c4 + 2][p] = f2bf(o[2]);
        tl[c4 + 3][p] = f2bf(o[3]);
    }
    __syncthreads();
    u16* dst = xt + (size_t)b * 131072 + ch * 128;
    #pragma unroll
    for (int i = 0; i < 8; ++i) {
        int d = (tid >> 4) + i * 16, c8 = (tid & 15) * 8;
        *(uint4*)(dst + (size_t)d * 1024 + c8) = *(const uint4*)&tl[d][c8];
    }
}

// ---------------- K2: Q/K projection (MFMA bf16, bf16 weights) ----------------
__global__ __launch_bounds__(256) void k_proj(const u16* __restrict__ xbf,
    const u16* __restrict__ wqk,
    u16* __restrict__ q_bf, u16* __restrict__ kt_bf)
{
    int tid = threadIdx.x;
    int w = tid >> 6, l = tid & 63, h = l >> 4, ln = l & 15;
    int t0 = blockIdx.x * 64 + w * 16;
    int o0 = blockIdx.y * 64;
    short8 a[4];
    #pragma unroll
    for (int s = 0; s < 4; ++s)
        a[s] = *(const short8*)(xbf + (size_t)(t0 + ln) * 128 + s * 32 + h * 8);
    f32x4 acc[4];
    #pragma unroll
    for (int n = 0; n < 4; ++n) acc[n] = f32x4{0.f, 0.f, 0.f, 0.f};
    #pragma unroll
    for (int n = 0; n < 4; ++n) {
        const u16* wsrc = wqk + (size_t)(o0 + n * 16 + ln) * 128;
        #pragma unroll
        for (int s = 0; s < 4; ++s) {
            short8 bf = *(const short8*)(wsrc + s * 32 + h * 8);
            acc[n] = mfma16(a[s], bf, acc[n]);
        }
    }
    bool isq = (o0 < 1024);
    float oscale = isq ? QSCALE : 1.0f;
    int head = (o0 & 1023) >> 7;
    int od_base = (o0 & 127);
    u16* basep = isq ? q_bf : kt_bf;
    #pragma unroll
    for (int n = 0; n < 4; ++n) {
        int d0 = od_base + n * 16 + ln;
        #pragma unroll
        for (int r = 0; r < 4; ++r) {
            int t = t0 + h * 4 + r;
            int b = t >> 10, pos = t & 1023;
            size_t row;
            if (isq) row = (size_t)(b * 8 + head) * 1024 + pos;
            else { int I = pos >> 5, J = pos & 31; row = (size_t)(b * 8 + head) * 1024 + (J * 32 + I); }
            basep[row * 128 + d0] = f2bf(acc[n][r] * oscale);
        }
    }
}

// ---------------- K3: bias GEMMs -> rbias[J][K], cbias[J][L] (pre-gathered) ----
__global__ __launch_bounds__(256) void k_bias(const u16* __restrict__ q_bf,
    const float* __restrict__ row_emb, const float* __restrict__ col_emb,
    float* __restrict__ rbias, float* __restrict__ cbias)
{
    __shared__ __align__(16) float cbf[32][68];
    int tid = threadIdx.x;
    int w = tid >> 6, l = tid & 63, h = l >> 4, ln = l & 15;
    int blk = blockIdx.x;
    int bh = blk >> 5, I = blk & 31;
    const u16* qb = q_bf + ((size_t)bh * 1024 + I * 32) * 128;
    size_t obase = (size_t)blk * 1024;
    if (w < 2) {
        short8 a0 = *(const short8*)(qb + (size_t)(w * 16 + ln) * 128 + h * 8);
        short8 a1 = *(const short8*)(qb + (size_t)(w * 16 + ln) * 128 + 32 + h * 8);
        f32x4 o[2] = {f32x4{0,0,0,0}, f32x4{0,0,0,0}};
        #pragma unroll
        for (int n = 0; n < 2; ++n) {
            int K = n * 16 + ln;
            const float* e = row_emb + (size_t)(K - I + 31) * 64 + h * 8;
            o[n] = mfma16(a0, cvt8(e), o[n]);
            o[n] = mfma16(a1, cvt8(e + 32), o[n]);
        }
        #pragma unroll
        for (int n = 0; n < 2; ++n)
            #pragma unroll
            for (int r = 0; r < 4; ++r)
                rbias[obase + (size_t)(w * 16 + h * 4 + r) * 32 + n * 16 + ln] = o[n][r];
    } else {
        int m = w - 2;
        short8 a0 = *(const short8*)(qb + (size_t)(m * 16 + ln) * 128 + 64 + h * 8);
        short8 a1 = *(const short8*)(qb + (size_t)(m * 16 + ln) * 128 + 96 + h * 8);
        f32x4 o[4] = {f32x4{0,0,0,0}, f32x4{0,0,0,0}, f32x4{0,0,0,0}, f32x4{0,0,0,0}};
        #pragma unroll
        for (int n = 0; n < 4; ++n) {
            int p = n * 16 + ln;
            if (p > 62) p = 62;            // clamp: p=63 never consumed
            const float* e = col_emb + (size_t)p * 64 + h * 8;
            o[n] = mfma16(a0, cvt8(e), o[n]);
            o[n] = mfma16(a1, cvt8(e + 32), o[n]);
        }
        #pragma unroll
        for (int n = 0; n < 4; ++n)
            #pragma unroll
            for (int r = 0; r < 4; ++r)
                cbf[m * 16 + h * 4 + r][n * 16 + ln] = o[n][r];
    }
    __syncthreads();
    int J = tid >> 3, L0 = (tid & 7) * 4;
    float4 g;
    g.x = cbf[J][L0 + 0 - J + 31];
    g.y = cbf[J][L0 + 1 - J + 31];
    g.z = cbf[J][L0 + 2 - J + 31];
    g.w = cbf[J][L0 + 3 - J + 31];
    *(float4*)(cbias + obase + (size_t)J * 32 + L0) = g;
}

// ---------------- K4: fused scores + softmax + PV (async kt staging) ----------
// R16 = R13 exactly (best k_attn, 161 us) with ONE change: the probs drain is
// moved AFTER PV+ctx. Drain ds_reads no longer queue ahead of PV ds_reads in
// the lgkm pipe, so PV's MFMAs start immediately post-barrier; drain stores
// land in the kernel tail where they overlap the next block's kt staging.
__global__ __launch_bounds__(512, 4) void k_attn(const u16* __restrict__ q_bf,
    const u16* __restrict__ kt_bf, const u16* __restrict__ xt_bf,
    const float* __restrict__ rbias, const float* __restrict__ cbias,
    float* __restrict__ probs, u16* __restrict__ ctx_bf)
{
    __shared__ __align__(16) char KT[8 * 8192];   // per-wave 8 KB: kt chunks, then P~
    __shared__ float wred[256];                   // partial sums [w*32 + J]

    int tid = threadIdx.x;
    int w = tid >> 6, l = tid & 63, h = l >> 4, ln = l & 15;
    int flat = blockIdx.x;
    int bh = flat >> 5, I = flat & 31;
    int b = bh >> 3, head = bh & 7;
    int kk0 = w * 128;
    char* reg = KT + w * 8192;
    const char* ktg = (const char*)(kt_bf + ((size_t)bh * 1024 + kk0) * 128);  // 32 KB span
    int d0 = w * 16;
    const u16* xb = xt_bf + (size_t)b * 131072 + (size_t)(d0 + ln) * 1024 + h * 8;

    // ---- prologue VMEM (retire before chunk0 consumed): bias + q ----
    const float* rbase = rbias + (size_t)(bh * 32 + I) * 1024;
    const float* cbase = cbias + (size_t)(bh * 32 + I) * 1024;
    f32x4 rbr[2][2], cbr[2];
    #pragma unroll
    for (int n = 0; n < 2; ++n) {
        int J = n * 16 + ln;
        rbr[n][0] = *(const f32x4*)(rbase + J * 32 + h * 4);
        rbr[n][1] = *(const f32x4*)(rbase + J * 32 + 16 + h * 4);
        cbr[n]    = *(const f32x4*)(cbase + J * 32 + w * 4);
    }
    const u16* qbase = q_bf + ((size_t)bh * 1024 + I * 32) * 128;
    short8 q0[4], q1[4];
    #pragma unroll
    for (int s = 0; s < 4; ++s) {
        q0[s] = *(const short8*)(qbase + (size_t)ln * 128 + s * 32 + h * 8);
        q1[s] = *(const short8*)(qbase + (size_t)(16 + ln) * 128 + s * 32 + h * 8);
    }

    // ---- stage helper: chunk c (16 kk rows, 4 KB) -> buf (0/1), 4 DMA instrs.
    //      source swizzled by involution f(o) = o ^ (((o>>8)&7)<<4). ----
    auto stage_chunk = [&](int c, int buf) {
        const char* gs = ktg + c * 4096;
        char* ld = reg + buf * 4096;
        #pragma unroll
        for (int i = 0; i < 4; ++i) {
            int key = ((i * 4 + (l >> 4)) & 7) << 4;
            int o = i * 1024 + l * 16;
            gload_lds16(gs + (o ^ key), ld + i * 1024);
        }
    };
    stage_chunk(0, 0);
    stage_chunk(1, 1);

    // ---- phase 1: S^T = K Q^T, software-pipelined over 8 chunks ----
    f32x4 acc[2][8];
    #pragma unroll
    for (int n = 0; n < 2; ++n)
        #pragma unroll
        for (int t = 0; t < 8; ++t) acc[n][t] = f32x4{0.f, 0.f, 0.f, 0.f};
    int xk = (ln & 7) << 4;
    #pragma unroll
    for (int c = 0; c < 8; ++c) {
        if (c < 7) asm volatile("s_waitcnt vmcnt(4)" ::: "memory");
        else       asm volatile("s_waitcnt vmcnt(0)" ::: "memory");
        const char* cb = reg + (c & 1) * 4096;
        short8 kf[4];
        #pragma unroll
        for (int s = 0; s < 4; ++s)
            kf[s] = *(const short8*)(cb + ((ln * 256 + s * 64 + h * 16) ^ xk));
        asm volatile("s_waitcnt lgkmcnt(0)" ::: "memory");
        __builtin_amdgcn_sched_barrier(0);
        if (c + 2 < 8) stage_chunk(c + 2, c & 1);
        #pragma unroll
        for (int s = 0; s < 4; ++s) {
            acc[0][c] = mfma16(kf[s], q0[s], acc[0][c]);
            acc[1][c] = mfma16(kf[s], q1[s], acc[1][c]);
        }
    }

    // ---- bias + exp2 + partial row-sum + P~ store into own region ----
    // P~ layout: row J (256 B pitch), kk-local, phys = logical ^ ((J&7)<<4).
    #pragma unroll
    for (int n = 0; n < 2; ++n) {
        int J = n * 16 + ln;
        float sum = 0.f;
        #pragma unroll
        for (int t = 0; t < 8; ++t) {
            float cbv = cbr[n][t >> 1];
            float p0 = exp2f(acc[n][t][0] + rbr[n][t & 1][0] + cbv);
            float p1 = exp2f(acc[n][t][1] + rbr[n][t & 1][1] + cbv);
            float p2 = exp2f(acc[n][t][2] + rbr[n][t & 1][2] + cbv);
            float p3 = exp2f(acc[n][t][3] + rbr[n][t & 1][3] + cbv);
            sum += (p0 + p1) + (p2 + p3);
            *(uint2*)(reg + ((J * 256 + t * 32 + h * 8) ^ xk)) =
                make_uint2(cvtpk(p0, p1), cvtpk(p2, p3));
        }
        sum += __shfl_xor(sum, 16);
        sum += __shfl_xor(sum, 32);
        if (l < 16) wred[w * 32 + J] = sum;
    }
    __syncthreads();   // the ONLY barrier: all P~ slices + wred complete

    // ---- per-thread row sums (broadcast f32x4 LDS reads) ----
    f32x4 sum0 = f32x4{0.f, 0.f, 0.f, 0.f};
    f32x4 sum1 = f32x4{0.f, 0.f, 0.f, 0.f};
    #pragma unroll
    for (int w2 = 0; w2 < 8; ++w2) {
        sum0 += *(const f32x4*)&wred[w2 * 32 + h * 4];
        sum1 += *(const f32x4*)&wred[w2 * 32 + 16 + h * 4];
    }
    int j = tid >> 4;
    float sd = 0.f;
    #pragma unroll
    for (int w2 = 0; w2 < 8; ++w2) sd += wred[w2 * 32 + j];
    float invd = 1.0f / sd;

    // ---- PV: ctx = P~ @ X  (wave w -> d-span w*16), starts right at barrier ----
    f32x4 cacc[2] = {f32x4{0,0,0,0}, f32x4{0,0,0,0}};
    #pragma unroll
    for (int ks = 0; ks < 32; ++ks) {
        short8 xf8 = *(const short8*)(xb + ks * 32);
        #pragma unroll
        for (int m = 0; m < 2; ++m) {
            short8 pa = *(const short8*)(KT + (ks >> 2) * 8192 +
                (((m * 16 + ln) * 256 + (ks & 3) * 64 + h * 16) ^ xk));
            cacc[m] = mfma16(pa, xf8, cacc[m]);
        }
    }
    #pragma unroll
    for (int m = 0; m < 2; ++m)
        #pragma unroll
        for (int r = 0; r < 4; ++r) {
            int J = m * 16 + h * 4 + r;
            float inv = 1.0f / (m ? sum1[r] : sum0[r]);
            ctx_bf[((size_t)(b * 32 + J) * 32 + I) * 1024 + head * 128 + d0 + ln] =
                f2bf(cacc[m][r] * inv);
        }

    // ---- probs drain from LDS, coalesced, in the kernel TAIL (overlaps the
    //      next block's kt staging; PV no longer waits behind these ds_reads) ----
    {
        float* prow = probs + ((((size_t)(b * 32 + j) * 32 + I) * 8 + head) << 10);
        int jx = (j & 7) << 4;
        #pragma unroll
        for (int i = 0; i < 8; ++i) {
            int kk = i * 128 + (tid & 15) * 8;
            short8 pv = *(const short8*)(KT + i * 8192 +
                            ((j * 256 + (tid & 15) * 16) ^ jx));
            float4 o0, o1;
            o0.x = sbf2f(pv[0]) * invd; o0.y = sbf2f(pv[1]) * invd;
            o0.z = sbf2f(pv[2]) * invd; o0.w = sbf2f(pv[3]) * invd;
            o1.x = sbf2f(pv[4]) * invd; o1.y = sbf2f(pv[5]) * invd;
            o1.z = sbf2f(pv[6]) * invd; o1.w = sbf2f(pv[7]) * invd;
            *(float4*)(prow + kk)     = o0;
            *(float4*)(prow + kk + 4) = o1;
        }
    }
}

// ---------------- K7: output = ctx @ Wv^T + bv + x (MFMA) ----------------
__global__ __launch_bounds__(256) void k_out(const u16* __restrict__ ctx_bf,
    const u16* __restrict__ wv_bf, const float* __restrict__ bv,
    const float* __restrict__ xf, float* __restrict__ out)
{
    int tid = threadIdx.x;
    int w = tid >> 6, l = tid & 63, h = l >> 4, ln = l & 15;
    int wm = w >> 1, wn = w & 1;
    int t0 = blockIdx.x * 32 + wm * 16;
    int o0 = blockIdx.y * 64 + wn * 32;
    f32x4 acc[2] = {f32x4{0,0,0,0}, f32x4{0,0,0,0}};
    for (int ks = 0; ks < 32; ++ks) {
        short8 a = *(const short8*)(ctx_bf + (size_t)(t0 + ln) * 1024 + ks * 32 + h * 8);
        #pragma unroll
        for (int nt = 0; nt < 2; ++nt) {
            short8 bb = *(const short8*)(wv_bf + (size_t)(o0 + nt * 16 + ln) * 1024 + ks * 32 + h * 8);
            acc[nt] = mfma16(a, bb, acc[nt]);
        }
    }
    #pragma unroll
    for (int nt = 0; nt < 2; ++nt) {
        int o = o0 + nt * 16 + ln;
        float bvv = bv[o];
        #pragma unroll
        for (int r = 0; r < 4; ++r) {
            int t = t0 + h * 4 + r;
            out[(size_t)t * 128 + o] = acc[nt][r] + bvv + xf[(size_t)t * 128 + o];
        }
    }
}

extern "C" void kernel_launch(void* const* d_in, const int* in_sizes, int n_in,
                              void* d_out, int out_size, void* d_ws, size_t ws_size,
                              hipStream_t stream) {
    (void)in_sizes; (void)n_in; (void)out_size; (void)ws_size;
    const float* hs      = (const float*)d_in[0];
    const float* row_emb = (const float*)d_in[1];
    const float* col_emb = (const float*)d_in[2];
    const float* Wq      = (const float*)d_in[3];
    const float* Wk      = (const float*)d_in[4];
    const float* Wv      = (const float*)d_in[5];
    const float* bv      = (const float*)d_in[6];
    const float* ln_g    = (const float*)d_in[7];
    const float* ln_b    = (const float*)d_in[8];

    float* out   = (float*)d_out;
    float* probs = out + 1048576;

    char* ws = (char*)d_ws;
    float* xf     = (float*)(ws);                      //  4 MB
    u16*   xbf    = (u16*)(ws + 4194304);              //  2 MB
    u16*   q_bf   = (u16*)(ws + 6291456);              // 16 MB
    u16*   kt_bf  = (u16*)(ws + 23068672);             // 16 MB
    u16*   xt     = (u16*)(ws + 39845888);             //  2 MB
    u16*   wqk_bf = (u16*)(ws + 41943040);             // 512 KB
    u16*   wv_bf  = (u16*)(ws + 42467328);             // 256 KB
    u16*   ctx    = (u16*)(ws + 42729472);             // 16 MB
    float* rbias  = (float*)(ws + 59506688);           //  8 MB
    float* cbias  = (float*)(ws + 67895296);           //  8 MB  (total 72.75 MB)

    k_wcvt <<<384, 256, 0, stream>>>(Wq, Wk, Wv, wqk_bf, wv_bf);
    k_lnxt <<<dim3(8, 8), 256, 0, stream>>>(hs, ln_g, ln_b, xf, xbf, xt);
    k_proj <<<dim3(128, 32), 256, 0, stream>>>(xbf, wqk_bf, q_bf, kt_bf);
    k_bias <<<2048, 256, 0, stream>>>(q_bf, row_emb, col_emb, rbias, cbias);
    k_attn <<<2048, 512, 0, stream>>>(q_bf, kt_bf, xt, rbias, cbias, probs, ctx);
    k_out  <<<dim3(256, 2), 256, 0, stream>>>(ctx, wv_bf, bv, xf, out);
}

// Round 17
// 250.250 us; speedup vs baseline: 1.0818x; 1.0051x over previous
//
#include <hip/hip_runtime.h>
#include <hip/hip_bf16.h>

#define HEADS 8
#define D 128
// log2(e) / sqrt(128): q is pre-scaled by this so scores are in exp2 domain.
#define QSCALE 0.12751743f

typedef unsigned short u16;
typedef unsigned int u32;
typedef __attribute__((ext_vector_type(8))) short short8;
typedef __attribute__((ext_vector_type(4))) float f32x4;

static __device__ inline float sbf2f(short s) {
    return __uint_as_float(((u32)(unsigned short)s) << 16);
}
static __device__ inline u16 f2bf(float f) {
    u32 u = __float_as_uint(f);
    return (u16)((u + 0x7FFFu + ((u >> 16) & 1u)) >> 16);
}
static __device__ inline u32 pk2bf(float a, float b) {
    return (u32)f2bf(a) | ((u32)f2bf(b) << 16);
}
// hardware v_cvt_pk_bf16_f32 path
static __device__ inline u32 cvtpk(float a, float b) {
    union { __hip_bfloat162 h; u32 u; } x;
    x.h = __float22bfloat162_rn(make_float2(a, b));
    return x.u;
}
static __device__ inline f32x4 mfma16(short8 a, short8 b, f32x4 c) {
    return __builtin_amdgcn_mfma_f32_16x16x32_bf16(a, b, c, 0, 0, 0);
}
// load 8 consecutive f32 and convert to a bf16 MFMA fragment
static __device__ inline short8 cvt8(const float* e) {
    f32x4 v0 = *(const f32x4*)e;
    f32x4 v1 = *(const f32x4*)(e + 4);
    union { uint4 u; short8 s; } x;
    x.u = make_uint4(pk2bf(v0[0], v0[1]), pk2bf(v0[2], v0[3]),
                     pk2bf(v1[0], v1[1]), pk2bf(v1[2], v1[3]));
    return x.s;
}
// async global->LDS, 16B per lane. Dest = uniform base + lane*16 (HW rule).
static __device__ __forceinline__ void gload_lds16(const void* g, void* l) {
    __builtin_amdgcn_global_load_lds(
        (const __attribute__((address_space(1))) u32*)g,
        (__attribute__((address_space(3))) u32*)(u32)(uintptr_t)l,
        16, 0, 0);
}

// ---------------- K1: fused {Wq/Wk/Wv cvt} + {LayerNorm + transpose} ----------
// blocks 0..383: weight conversion; blocks 384..447: LN + xbf + xt.
__global__ __launch_bounds__(256) void k_init(const float* __restrict__ hs,
    const float* __restrict__ g, const float* __restrict__ bb,
    const float* __restrict__ Wq, const float* __restrict__ Wk,
    const float* __restrict__ Wv,
    float* __restrict__ xf, u16* __restrict__ xbf, u16* __restrict__ xt,
    u16* __restrict__ wqk, u16* __restrict__ wv)
{
    __shared__ __align__(16) u16 tl[128][136];
    int bid = blockIdx.x;
    int tid = threadIdx.x;
    if (bid < 384) {
        int idx = (bid * 256 + tid) * 4;   // 393216 floats total
        const float* src;
        u16* dst;
        if (idx < 131072)      { src = Wq + idx;            dst = wqk + idx; }
        else if (idx < 262144) { src = Wk + (idx - 131072); dst = wqk + idx; }
        else                   { src = Wv + (idx - 262144); dst = wv + (idx - 262144); }
        f32x4 v = *(const f32x4*)src;
        *(uint2*)dst = make_uint2(pk2bf(v[0], v[1]), pk2bf(v[2], v[3]));
        return;
    }
    int blk = bid - 384;
    int b = blk >> 3, ch = blk & 7;
    int c4 = (tid & 31) * 4;
    f32x4 g4 = *(const f32x4*)(g + c4);
    f32x4 b4 = *(const f32x4*)(bb + c4);
    const float* src = hs + ((size_t)b * 1024 + ch * 128) * 128;
    #pragma unroll
    for (int it = 0; it < 16; ++it) {
        int p = (tid >> 5) + it * 8;
        f32x4 v = *(const f32x4*)(src + (size_t)p * 128 + c4);
        float s1 = (v[0] + v[1]) + (v[2] + v[3]);
        float s2 = (v[0] * v[0] + v[1] * v[1]) + (v[2] * v[2] + v[3] * v[3]);
        #pragma unroll
        for (int off = 1; off < 32; off <<= 1) {
            s1 += __shfl_xor(s1, off);
            s2 += __shfl_xor(s2, off);
        }
        float mu  = s1 * 0.0078125f;
        float var = s2 * 0.0078125f - mu * mu;
        float inv = rsqrtf(var + 1e-5f);
        f32x4 o;
        #pragma unroll
        for (int q = 0; q < 4; ++q) o[q] = (v[q] - mu) * inv * g4[q] + b4[q];
        size_t row = (size_t)b * 1024 + ch * 128 + p;
        *(f32x4*)(xf + row * 128 + c4) = o;
        *(uint2*)(xbf + row * 128 + c4) = make_uint2(pk2bf(o[0], o[1]), pk2bf(o[2], o[3]));
        tl[c4 + 0][p] = f2bf(o[0]);
        tl[c4 + 1][p] = f2bf(o[1]);
        tl[c4 + 2][p] = f2bf(o[2]);
        tl[c4 + 3][p] = f2bf(o[3]);
    }
    __syncthreads();
    u16* dst = xt + (size_t)b * 131072 + ch * 128;
    #pragma unroll
    for (int i = 0; i < 8; ++i) {
        int d = (tid >> 4) + i * 16, c8 = (tid & 15) * 8;
        *(uint4*)(dst + (size_t)d * 1024 + c8) = *(const uint4*)&tl[d][c8];
    }
}

// ---------------- K2: Q/K projection (MFMA, swapped operands) ----------------
// A = weight rows (o), B = token rows -> C[row=o_local, col=token]: each lane
// owns token t0+ln and 4 CONSECUTIVE d per n-tile -> packed uint2 stores
// (4x8B vs old 16x2B scalar). Q outputs pre-scaled by QSCALE.
__global__ __launch_bounds__(256) void k_proj(const u16* __restrict__ xbf,
    const u16* __restrict__ wqk,
    u16* __restrict__ q_bf, u16* __restrict__ kt_bf)
{
    int tid = threadIdx.x;
    int w = tid >> 6, l = tid & 63, h = l >> 4, ln = l & 15;
    int t0 = blockIdx.x * 64 + w * 16;
    int o0 = blockIdx.y * 64;
    // B operand: token fragments (token = t0 + ln)
    short8 tb[4];
    #pragma unroll
    for (int s = 0; s < 4; ++s)
        tb[s] = *(const short8*)(xbf + (size_t)(t0 + ln) * 128 + s * 32 + h * 8);
    f32x4 acc[4];
    #pragma unroll
    for (int n = 0; n < 4; ++n) acc[n] = f32x4{0.f, 0.f, 0.f, 0.f};
    #pragma unroll
    for (int n = 0; n < 4; ++n) {
        const u16* wsrc = wqk + (size_t)(o0 + n * 16 + ln) * 128;
        #pragma unroll
        for (int s = 0; s < 4; ++s) {
            short8 wf = *(const short8*)(wsrc + s * 32 + h * 8);
            acc[n] = mfma16(wf, tb[s], acc[n]);   // A=weights, B=tokens
        }
    }
    bool isq = (o0 < 1024);
    float os = isq ? QSCALE : 1.0f;
    int head = (o0 & 1023) >> 7;
    int od = (o0 & 127);
    u16* basep = isq ? q_bf : kt_bf;
    int t = t0 + ln;
    int b = t >> 10, pos = t & 1023;
    size_t row;
    if (isq) row = (size_t)(b * 8 + head) * 1024 + pos;
    else { int I = pos >> 5, J = pos & 31; row = (size_t)(b * 8 + head) * 1024 + (J * 32 + I); }
    u16* dst = basep + row * 128 + od + h * 4;
    #pragma unroll
    for (int n = 0; n < 4; ++n) {
        *(uint2*)(dst + n * 16) = make_uint2(
            pk2bf(acc[n][0] * os, acc[n][1] * os),
            pk2bf(acc[n][2] * os, acc[n][3] * os));
    }
}

// ---------------- K3: bias GEMMs -> rbias[J][K], cbias[J][L] (pre-gathered) ----
__global__ __launch_bounds__(256) void k_bias(const u16* __restrict__ q_bf,
    const float* __restrict__ row_emb, const float* __restrict__ col_emb,
    float* __restrict__ rbias, float* __restrict__ cbias)
{
    __shared__ __align__(16) float cbf[32][68];
    int tid = threadIdx.x;
    int w = tid >> 6, l = tid & 63, h = l >> 4, ln = l & 15;
    int blk = blockIdx.x;
    int bh = blk >> 5, I = blk & 31;
    const u16* qb = q_bf + ((size_t)bh * 1024 + I * 32) * 128;
    size_t obase = (size_t)blk * 1024;
    if (w < 2) {
        short8 a0 = *(const short8*)(qb + (size_t)(w * 16 + ln) * 128 + h * 8);
        short8 a1 = *(const short8*)(qb + (size_t)(w * 16 + ln) * 128 + 32 + h * 8);
        f32x4 o[2] = {f32x4{0,0,0,0}, f32x4{0,0,0,0}};
        #pragma unroll
        for (int n = 0; n < 2; ++n) {
            int K = n * 16 + ln;
            const float* e = row_emb + (size_t)(K - I + 31) * 64 + h * 8;
            o[n] = mfma16(a0, cvt8(e), o[n]);
            o[n] = mfma16(a1, cvt8(e + 32), o[n]);
        }
        #pragma unroll
        for (int n = 0; n < 2; ++n)
            #pragma unroll
            for (int r = 0; r < 4; ++r)
                rbias[obase + (size_t)(w * 16 + h * 4 + r) * 32 + n * 16 + ln] = o[n][r];
    } else {
        int m = w - 2;
        short8 a0 = *(const short8*)(qb + (size_t)(m * 16 + ln) * 128 + 64 + h * 8);
        short8 a1 = *(const short8*)(qb + (size_t)(m * 16 + ln) * 128 + 96 + h * 8);
        f32x4 o[4] = {f32x4{0,0,0,0}, f32x4{0,0,0,0}, f32x4{0,0,0,0}, f32x4{0,0,0,0}};
        #pragma unroll
        for (int n = 0; n < 4; ++n) {
            int p = n * 16 + ln;
            if (p > 62) p = 62;            // clamp: p=63 never consumed
            const float* e = col_emb + (size_t)p * 64 + h * 8;
            o[n] = mfma16(a0, cvt8(e), o[n]);
            o[n] = mfma16(a1, cvt8(e + 32), o[n]);
        }
        #pragma unroll
        for (int n = 0; n < 4; ++n)
            #pragma unroll
            for (int r = 0; r < 4; ++r)
                cbf[m * 16 + h * 4 + r][n * 16 + ln] = o[n][r];
    }
    __syncthreads();
    int J = tid >> 3, L0 = (tid & 7) * 4;
    float4 g;
    g.x = cbf[J][L0 + 0 - J + 31];
    g.y = cbf[J][L0 + 1 - J + 31];
    g.z = cbf[J][L0 + 2 - J + 31];
    g.w = cbf[J][L0 + 3 - J + 31];
    *(float4*)(cbias + obase + (size_t)J * 32 + L0) = g;
}

// ---------------- K4: fused scores + softmax + PV (async kt + setprio) --------
// R17 = R16 + T5 s_setprio around the MFMA clusters (blocks/waves are
// phase-desynchronized -> scheduler can favor MFMA-issuing waves; +4-7%
// measured on attention in this regime).
__global__ __launch_bounds__(512, 4) void k_attn(const u16* __restrict__ q_bf,
    const u16* __restrict__ kt_bf, const u16* __restrict__ xt_bf,
    const float* __restrict__ rbias, const float* __restrict__ cbias,
    float* __restrict__ probs, u16* __restrict__ ctx_bf)
{
    __shared__ __align__(16) char KT[8 * 8192];   // per-wave 8 KB: kt chunks, then P~
    __shared__ float wred[256];                   // partial sums [w*32 + J]

    int tid = threadIdx.x;
    int w = tid >> 6, l = tid & 63, h = l >> 4, ln = l & 15;
    int flat = blockIdx.x;
    int bh = flat >> 5, I = flat & 31;
    int b = bh >> 3, head = bh & 7;
    int kk0 = w * 128;
    char* reg = KT + w * 8192;
    const char* ktg = (const char*)(kt_bf + ((size_t)bh * 1024 + kk0) * 128);  // 32 KB span
    int d0 = w * 16;
    const u16* xb = xt_bf + (size_t)b * 131072 + (size_t)(d0 + ln) * 1024 + h * 8;

    // ---- prologue VMEM (retire before chunk0 consumed): bias + q ----
    const float* rbase = rbias + (size_t)(bh * 32 + I) * 1024;
    const float* cbase = cbias + (size_t)(bh * 32 + I) * 1024;
    f32x4 rbr[2][2], cbr[2];
    #pragma unroll
    for (int n = 0; n < 2; ++n) {
        int J = n * 16 + ln;
        rbr[n][0] = *(const f32x4*)(rbase + J * 32 + h * 4);
        rbr[n][1] = *(const f32x4*)(rbase + J * 32 + 16 + h * 4);
        cbr[n]    = *(const f32x4*)(cbase + J * 32 + w * 4);
    }
    const u16* qbase = q_bf + ((size_t)bh * 1024 + I * 32) * 128;
    short8 q0[4], q1[4];
    #pragma unroll
    for (int s = 0; s < 4; ++s) {
        q0[s] = *(const short8*)(qbase + (size_t)ln * 128 + s * 32 + h * 8);
        q1[s] = *(const short8*)(qbase + (size_t)(16 + ln) * 128 + s * 32 + h * 8);
    }

    // ---- stage helper: chunk c (16 kk rows, 4 KB) -> buf (0/1), 4 DMA instrs.
    //      source swizzled by involution f(o) = o ^ (((o>>8)&7)<<4). ----
    auto stage_chunk = [&](int c, int buf) {
        const char* gs = ktg + c * 4096;
        char* ld = reg + buf * 4096;
        #pragma unroll
        for (int i = 0; i < 4; ++i) {
            int key = ((i * 4 + (l >> 4)) & 7) << 4;
            int o = i * 1024 + l * 16;
            gload_lds16(gs + (o ^ key), ld + i * 1024);
        }
    };
    stage_chunk(0, 0);
    stage_chunk(1, 1);

    // ---- phase 1: S^T = K Q^T, software-pipelined over 8 chunks ----
    f32x4 acc[2][8];
    #pragma unroll
    for (int n = 0; n < 2; ++n)
        #pragma unroll
        for (int t = 0; t < 8; ++t) acc[n][t] = f32x4{0.f, 0.f, 0.f, 0.f};
    int xk = (ln & 7) << 4;
    #pragma unroll
    for (int c = 0; c < 8; ++c) {
        if (c < 7) asm volatile("s_waitcnt vmcnt(4)" ::: "memory");
        else       asm volatile("s_waitcnt vmcnt(0)" ::: "memory");
        const char* cb = reg + (c & 1) * 4096;
        short8 kf[4];
        #pragma unroll
        for (int s = 0; s < 4; ++s)
            kf[s] = *(const short8*)(cb + ((ln * 256 + s * 64 + h * 16) ^ xk));
        asm volatile("s_waitcnt lgkmcnt(0)" ::: "memory");
        __builtin_amdgcn_sched_barrier(0);
        if (c + 2 < 8) stage_chunk(c + 2, c & 1);
        __builtin_amdgcn_s_setprio(1);
        #pragma unroll
        for (int s = 0; s < 4; ++s) {
            acc[0][c] = mfma16(kf[s], q0[s], acc[0][c]);
            acc[1][c] = mfma16(kf[s], q1[s], acc[1][c]);
        }
        __builtin_amdgcn_s_setprio(0);
    }

    // ---- bias + exp2 + partial row-sum + P~ store into own region ----
    // P~ layout: row J (256 B pitch), kk-local, phys = logical ^ ((J&7)<<4).
    #pragma unroll
    for (int n = 0; n < 2; ++n) {
        int J = n * 16 + ln;
        float sum = 0.f;
        #pragma unroll
        for (int t = 0; t < 8; ++t) {
            float cbv = cbr[n][t >> 1];
            float p0 = exp2f(acc[n][t][0] + rbr[n][t & 1][0] + cbv);
            float p1 = exp2f(acc[n][t][1] + rbr[n][t & 1][1] + cbv);
            float p2 = exp2f(acc[n][t][2] + rbr[n][t & 1][2] + cbv);
            float p3 = exp2f(acc[n][t][3] + rbr[n][t & 1][3] + cbv);
            sum += (p0 + p1) + (p2 + p3);
            *(uint2*)(reg + ((J * 256 + t * 32 + h * 8) ^ xk)) =
                make_uint2(cvtpk(p0, p1), cvtpk(p2, p3));
        }
        sum += __shfl_xor(sum, 16);
        sum += __shfl_xor(sum, 32);
        if (l < 16) wred[w * 32 + J] = sum;
    }
    __syncthreads();   // the ONLY barrier: all P~ slices + wred complete

    // ---- per-thread row sums (broadcast f32x4 LDS reads) ----
    f32x4 sum0 = f32x4{0.f, 0.f, 0.f, 0.f};
    f32x4 sum1 = f32x4{0.f, 0.f, 0.f, 0.f};
    #pragma unroll
    for (int w2 = 0; w2 < 8; ++w2) {
        sum0 += *(const f32x4*)&wred[w2 * 32 + h * 4];
        sum1 += *(const f32x4*)&wred[w2 * 32 + 16 + h * 4];
    }
    int j = tid >> 4;
    float sd = 0.f;
    #pragma unroll
    for (int w2 = 0; w2 < 8; ++w2) sd += wred[w2 * 32 + j];
    float invd = 1.0f / sd;

    // ---- PV: ctx = P~ @ X  (wave w -> d-span w*16), starts right at barrier ----
    f32x4 cacc[2] = {f32x4{0,0,0,0}, f32x4{0,0,0,0}};
    __builtin_amdgcn_s_setprio(1);
    #pragma unroll
    for (int ks = 0; ks < 32; ++ks) {
        short8 xf8 = *(const short8*)(xb + ks * 32);
        #pragma unroll
        for (int m = 0; m < 2; ++m) {
            short8 pa = *(const short8*)(KT + (ks >> 2) * 8192 +
                (((m * 16 + ln) * 256 + (ks & 3) * 64 + h * 16) ^ xk));
            cacc[m] = mfma16(pa, xf8, cacc[m]);
        }
    }
    __builtin_amdgcn_s_setprio(0);
    #pragma unroll
    for (int m = 0; m < 2; ++m)
        #pragma unroll
        for (int r = 0; r < 4; ++r) {
            int J = m * 16 + h * 4 + r;
            float inv = 1.0f / (m ? sum1[r] : sum0[r]);
            ctx_bf[((size_t)(b * 32 + J) * 32 + I) * 1024 + head * 128 + d0 + ln] =
                f2bf(cacc[m][r] * inv);
        }

    // ---- probs drain from LDS, coalesced, in the kernel TAIL (overlaps the
    //      next block's kt staging; PV no longer waits behind these ds_reads) ----
    {
        float* prow = probs + ((((size_t)(b * 32 + j) * 32 + I) * 8 + head) << 10);
        int jx = (j & 7) << 4;
        #pragma unroll
        for (int i = 0; i < 8; ++i) {
            int kk = i * 128 + (tid & 15) * 8;
            short8 pv = *(const short8*)(KT + i * 8192 +
                            ((j * 256 + (tid & 15) * 16) ^ jx));
            float4 o0, o1;
            o0.x = sbf2f(pv[0]) * invd; o0.y = sbf2f(pv[1]) * invd;
            o0.z = sbf2f(pv[2]) * invd; o0.w = sbf2f(pv[3]) * invd;
            o1.x = sbf2f(pv[4]) * invd; o1.y = sbf2f(pv[5]) * invd;
            o1.z = sbf2f(pv[6]) * invd; o1.w = sbf2f(pv[7]) * invd;
            *(float4*)(prow + kk)     = o0;
            *(float4*)(prow + kk + 4) = o1;
        }
    }
}

// ---------------- K7: output = ctx @ Wv^T + bv + x (MFMA) ----------------
__global__ __launch_bounds__(256) void k_out(const u16* __restrict__ ctx_bf,
    const u16* __restrict__ wv_bf, const float* __restrict__ bv,
    const float* __restrict__ xf, float* __restrict__ out)
{
    int tid = threadIdx.x;
    int w = tid >> 6, l = tid & 63, h = l >> 4, ln = l & 15;
    int wm = w >> 1, wn = w & 1;
    int t0 = blockIdx.x * 32 + wm * 16;
    int o0 = blockIdx.y * 64 + wn * 32;
    f32x4 acc[2] = {f32x4{0,0,0,0}, f32x4{0,0,0,0}};
    for (int ks = 0; ks < 32; ++ks) {
        short8 a = *(const short8*)(ctx_bf + (size_t)(t0 + ln) * 1024 + ks * 32 + h * 8);
        #pragma unroll
        for (int nt = 0; nt < 2; ++nt) {
            short8 bb = *(const short8*)(wv_bf + (size_t)(o0 + nt * 16 + ln) * 1024 + ks * 32 + h * 8);
            acc[nt] = mfma16(a, bb, acc[nt]);
        }
    }
    #pragma unroll
    for (int nt = 0; nt < 2; ++nt) {
        int o = o0 + nt * 16 + ln;
        float bvv = bv[o];
        #pragma unroll
        for (int r = 0; r < 4; ++r) {
            int t = t0 + h * 4 + r;
            out[(size_t)t * 128 + o] = acc[nt][r] + bvv + xf[(size_t)t * 128 + o];
        }
    }
}

extern "C" void kernel_launch(void* const* d_in, const int* in_sizes, int n_in,
                              void* d_out, int out_size, void* d_ws, size_t ws_size,
                              hipStream_t stream) {
    (void)in_sizes; (void)n_in; (void)out_size; (void)ws_size;
    const float* hs      = (const float*)d_in[0];
    const float* row_emb = (const float*)d_in[1];
    const float* col_emb = (const float*)d_in[2];
    const float* Wq      = (const float*)d_in[3];
    const float* Wk      = (const float*)d_in[4];
    const float* Wv      = (const float*)d_in[5];
    const float* bv      = (const float*)d_in[6];
    const float* ln_g    = (const float*)d_in[7];
    const float* ln_b    = (const float*)d_in[8];

    float* out   = (float*)d_out;
    float* probs = out + 1048576;

    char* ws = (char*)d_ws;
    float* xf     = (float*)(ws);                      //  4 MB
    u16*   xbf    = (u16*)(ws + 4194304);              //  2 MB
    u16*   q_bf   = (u16*)(ws + 6291456);              // 16 MB
    u16*   kt_bf  = (u16*)(ws + 23068672);             // 16 MB
    u16*   xt     = (u16*)(ws + 39845888);             //  2 MB
    u16*   wqk_bf = (u16*)(ws + 41943040);             // 512 KB
    u16*   wv_bf  = (u16*)(ws + 42467328);             // 256 KB
    u16*   ctx    = (u16*)(ws + 42729472);             // 16 MB
    float* rbias  = (float*)(ws + 59506688);           //  8 MB
    float* cbias  = (float*)(ws + 67895296);           //  8 MB  (total 72.75 MB)

    k_init <<<448, 256, 0, stream>>>(hs, ln_g, ln_b, Wq, Wk, Wv,
                                     xf, xbf, xt, wqk_bf, wv_bf);
    k_proj <<<dim3(128, 32), 256, 0, stream>>>(xbf, wqk_bf, q_bf, kt_bf);
    k_bias <<<2048, 256, 0, stream>>>(q_bf, row_emb, col_emb, rbias, cbias);
    k_attn <<<2048, 512, 0, stream>>>(q_bf, kt_bf, xt, rbias, cbias, probs, ctx);
    k_out  <<<dim3(256, 2), 256, 0, stream>>>(ctx, wv_bf, bv, xf, out);
}

// Round 18
// 249.527 us; speedup vs baseline: 1.0849x; 1.0029x over previous
//
#include <hip/hip_runtime.h>
#include <hip/hip_bf16.h>

#define HEADS 8
#define D 128
// log2(e) / sqrt(128): q is pre-scaled by this so scores are in exp2 domain.
#define QSCALE 0.12751743f

typedef unsigned short u16;
typedef unsigned int u32;
typedef __attribute__((ext_vector_type(8))) short short8;
typedef __attribute__((ext_vector_type(4))) float f32x4;

static __device__ inline float sbf2f(short s) {
    return __uint_as_float(((u32)(unsigned short)s) << 16);
}
static __device__ inline u16 f2bf(float f) {
    u32 u = __float_as_uint(f);
    return (u16)((u + 0x7FFFu + ((u >> 16) & 1u)) >> 16);
}
static __device__ inline u32 pk2bf(float a, float b) {
    return (u32)f2bf(a) | ((u32)f2bf(b) << 16);
}
// hardware v_cvt_pk_bf16_f32 path
static __device__ inline u32 cvtpk(float a, float b) {
    union { __hip_bfloat162 h; u32 u; } x;
    x.h = __float22bfloat162_rn(make_float2(a, b));
    return x.u;
}
static __device__ inline f32x4 mfma16(short8 a, short8 b, f32x4 c) {
    return __builtin_amdgcn_mfma_f32_16x16x32_bf16(a, b, c, 0, 0, 0);
}
// load 8 consecutive f32 and convert to a bf16 MFMA fragment
static __device__ inline short8 cvt8(const float* e) {
    f32x4 v0 = *(const f32x4*)e;
    f32x4 v1 = *(const f32x4*)(e + 4);
    union { uint4 u; short8 s; } x;
    x.u = make_uint4(pk2bf(v0[0], v0[1]), pk2bf(v0[2], v0[3]),
                     pk2bf(v1[0], v1[1]), pk2bf(v1[2], v1[3]));
    return x.s;
}
// async global->LDS, 16B per lane. Dest = uniform base + lane*16 (HW rule).
static __device__ __forceinline__ void gload_lds16(const void* g, void* l) {
    __builtin_amdgcn_global_load_lds(
        (const __attribute__((address_space(1))) u32*)g,
        (__attribute__((address_space(3))) u32*)(u32)(uintptr_t)l,
        16, 0, 0);
}

// ---------------- K1: fused {Wq/Wk/Wv cvt} + {LayerNorm + transpose} ----------
// blocks 0..383: weight conversion; blocks 384..447: LN + xbf + xt.
__global__ __launch_bounds__(256) void k_init(const float* __restrict__ hs,
    const float* __restrict__ g, const float* __restrict__ bb,
    const float* __restrict__ Wq, const float* __restrict__ Wk,
    const float* __restrict__ Wv,
    float* __restrict__ xf, u16* __restrict__ xbf, u16* __restrict__ xt,
    u16* __restrict__ wqk, u16* __restrict__ wv)
{
    __shared__ __align__(16) u16 tl[128][136];
    int bid = blockIdx.x;
    int tid = threadIdx.x;
    if (bid < 384) {
        int idx = (bid * 256 + tid) * 4;   // 393216 floats total
        const float* src;
        u16* dst;
        if (idx < 131072)      { src = Wq + idx;            dst = wqk + idx; }
        else if (idx < 262144) { src = Wk + (idx - 131072); dst = wqk + idx; }
        else                   { src = Wv + (idx - 262144); dst = wv + (idx - 262144); }
        f32x4 v = *(const f32x4*)src;
        *(uint2*)dst = make_uint2(pk2bf(v[0], v[1]), pk2bf(v[2], v[3]));
        return;
    }
    int blk = bid - 384;
    int b = blk >> 3, ch = blk & 7;
    int c4 = (tid & 31) * 4;
    f32x4 g4 = *(const f32x4*)(g + c4);
    f32x4 b4 = *(const f32x4*)(bb + c4);
    const float* src = hs + ((size_t)b * 1024 + ch * 128) * 128;
    #pragma unroll
    for (int it = 0; it < 16; ++it) {
        int p = (tid >> 5) + it * 8;
        f32x4 v = *(const f32x4*)(src + (size_t)p * 128 + c4);
        float s1 = (v[0] + v[1]) + (v[2] + v[3]);
        float s2 = (v[0] * v[0] + v[1] * v[1]) + (v[2] * v[2] + v[3] * v[3]);
        #pragma unroll
        for (int off = 1; off < 32; off <<= 1) {
            s1 += __shfl_xor(s1, off);
            s2 += __shfl_xor(s2, off);
        }
        float mu  = s1 * 0.0078125f;
        float var = s2 * 0.0078125f - mu * mu;
        float inv = rsqrtf(var + 1e-5f);
        f32x4 o;
        #pragma unroll
        for (int q = 0; q < 4; ++q) o[q] = (v[q] - mu) * inv * g4[q] + b4[q];
        size_t row = (size_t)b * 1024 + ch * 128 + p;
        *(f32x4*)(xf + row * 128 + c4) = o;
        *(uint2*)(xbf + row * 128 + c4) = make_uint2(pk2bf(o[0], o[1]), pk2bf(o[2], o[3]));
        tl[c4 + 0][p] = f2bf(o[0]);
        tl[c4 + 1][p] = f2bf(o[1]);
        tl[c4 + 2][p] = f2bf(o[2]);
        tl[c4 + 3][p] = f2bf(o[3]);
    }
    __syncthreads();
    u16* dst = xt + (size_t)b * 131072 + ch * 128;
    #pragma unroll
    for (int i = 0; i < 8; ++i) {
        int d = (tid >> 4) + i * 16, c8 = (tid & 15) * 8;
        *(uint4*)(dst + (size_t)d * 1024 + c8) = *(const uint4*)&tl[d][c8];
    }
}

// ---------------- K2: Q/K projection (MFMA, swapped operands) ----------------
// A = weight rows (o), B = token rows -> C[row=o_local, col=token]: each lane
// owns token t0+ln and 4 CONSECUTIVE d per n-tile -> packed uint2 stores.
__global__ __launch_bounds__(256) void k_proj(const u16* __restrict__ xbf,
    const u16* __restrict__ wqk,
    u16* __restrict__ q_bf, u16* __restrict__ kt_bf)
{
    int tid = threadIdx.x;
    int w = tid >> 6, l = tid & 63, h = l >> 4, ln = l & 15;
    int t0 = blockIdx.x * 64 + w * 16;
    int o0 = blockIdx.y * 64;
    short8 tb[4];
    #pragma unroll
    for (int s = 0; s < 4; ++s)
        tb[s] = *(const short8*)(xbf + (size_t)(t0 + ln) * 128 + s * 32 + h * 8);
    f32x4 acc[4];
    #pragma unroll
    for (int n = 0; n < 4; ++n) acc[n] = f32x4{0.f, 0.f, 0.f, 0.f};
    #pragma unroll
    for (int n = 0; n < 4; ++n) {
        const u16* wsrc = wqk + (size_t)(o0 + n * 16 + ln) * 128;
        #pragma unroll
        for (int s = 0; s < 4; ++s) {
            short8 wf = *(const short8*)(wsrc + s * 32 + h * 8);
            acc[n] = mfma16(wf, tb[s], acc[n]);   // A=weights, B=tokens
        }
    }
    bool isq = (o0 < 1024);
    float os = isq ? QSCALE : 1.0f;
    int head = (o0 & 1023) >> 7;
    int od = (o0 & 127);
    u16* basep = isq ? q_bf : kt_bf;
    int t = t0 + ln;
    int b = t >> 10, pos = t & 1023;
    size_t row;
    if (isq) row = (size_t)(b * 8 + head) * 1024 + pos;
    else { int I = pos >> 5, J = pos & 31; row = (size_t)(b * 8 + head) * 1024 + (J * 32 + I); }
    u16* dst = basep + row * 128 + od + h * 4;
    #pragma unroll
    for (int n = 0; n < 4; ++n) {
        *(uint2*)(dst + n * 16) = make_uint2(
            pk2bf(acc[n][0] * os, acc[n][1] * os),
            pk2bf(acc[n][2] * os, acc[n][3] * os));
    }
}

// ---------------- K3: col-bias GEMM only -> cbias[J][L] (pre-gathered) --------
// rb is now computed inside k_attn directly from row_emb.
// 4 waves: wave w -> m-tile (w&1), n-pair (w>>1)*2 + {0,1}.
__global__ __launch_bounds__(256) void k_cbias(const u16* __restrict__ q_bf,
    const float* __restrict__ col_emb, float* __restrict__ cbias)
{
    __shared__ __align__(16) float cbf[32][68];
    int tid = threadIdx.x;
    int w = tid >> 6, l = tid & 63, h = l >> 4, ln = l & 15;
    int blk = blockIdx.x;
    int bh = blk >> 5, I = blk & 31;
    const u16* qb = q_bf + ((size_t)bh * 1024 + I * 32) * 128;
    size_t obase = (size_t)blk * 1024;
    int m  = w & 1;
    int np = (w >> 1) * 2;
    short8 a0 = *(const short8*)(qb + (size_t)(m * 16 + ln) * 128 + 64 + h * 8);
    short8 a1 = *(const short8*)(qb + (size_t)(m * 16 + ln) * 128 + 96 + h * 8);
    f32x4 o[2] = {f32x4{0,0,0,0}, f32x4{0,0,0,0}};
    #pragma unroll
    for (int ni = 0; ni < 2; ++ni) {
        int p = (np + ni) * 16 + ln;
        if (p > 62) p = 62;            // clamp: p=63 never consumed
        const float* e = col_emb + (size_t)p * 64 + h * 8;
        o[ni] = mfma16(a0, cvt8(e), o[ni]);
        o[ni] = mfma16(a1, cvt8(e + 32), o[ni]);
    }
    #pragma unroll
    for (int ni = 0; ni < 2; ++ni)
        #pragma unroll
        for (int r = 0; r < 4; ++r)
            cbf[m * 16 + h * 4 + r][(np + ni) * 16 + ln] = o[ni][r];
    __syncthreads();
    int J = tid >> 3, L0 = (tid & 7) * 4;
    float4 gg;
    gg.x = cbf[J][L0 + 0 - J + 31];
    gg.y = cbf[J][L0 + 1 - J + 31];
    gg.z = cbf[J][L0 + 2 - J + 31];
    gg.w = cbf[J][L0 + 3 - J + 31];
    *(float4*)(cbias + obase + (size_t)J * 32 + L0) = gg;
}

// ---------------- K4: fused rb-GEMM + scores + softmax + PV (async kt) --------
// R18 = R16 structure (no setprio) + rb computed in-register: 8 MFMAs with
// A = row_emb rows (gathered at K-I+31, cvt8 from global, L1-hot) and B = the
// q fragments already loaded. Output layout matches consumption exactly:
// rbr[n][par][r] = rb[J=n*16+ln][K=par*16+h*4+r]. Kills the rbias buffer.
__global__ __launch_bounds__(512, 4) void k_attn(const u16* __restrict__ q_bf,
    const u16* __restrict__ kt_bf, const u16* __restrict__ xt_bf,
    const float* __restrict__ row_emb, const float* __restrict__ cbias,
    float* __restrict__ probs, u16* __restrict__ ctx_bf)
{
    __shared__ __align__(16) char KT[8 * 8192];   // per-wave 8 KB: kt chunks, then P~
    __shared__ float wred[256];                   // partial sums [w*32 + J]

    int tid = threadIdx.x;
    int w = tid >> 6, l = tid & 63, h = l >> 4, ln = l & 15;
    int flat = blockIdx.x;
    int bh = flat >> 5, I = flat & 31;
    int b = bh >> 3, head = bh & 7;
    int kk0 = w * 128;
    char* reg = KT + w * 8192;
    const char* ktg = (const char*)(kt_bf + ((size_t)bh * 1024 + kk0) * 128);  // 32 KB span
    int d0 = w * 16;
    const u16* xb = xt_bf + (size_t)b * 131072 + (size_t)(d0 + ln) * 1024 + h * 8;

    // ---- prologue VMEM: cb + q ----
    const float* cbase = cbias + (size_t)(bh * 32 + I) * 1024;
    f32x4 cbr[2];
    #pragma unroll
    for (int n = 0; n < 2; ++n)
        cbr[n] = *(const f32x4*)(cbase + (n * 16 + ln) * 32 + w * 4);
    const u16* qbase = q_bf + ((size_t)bh * 1024 + I * 32) * 128;
    short8 q0[4], q1[4];
    #pragma unroll
    for (int s = 0; s < 4; ++s) {
        q0[s] = *(const short8*)(qbase + (size_t)ln * 128 + s * 32 + h * 8);
        q1[s] = *(const short8*)(qbase + (size_t)(16 + ln) * 128 + s * 32 + h * 8);
    }

    // ---- stage helper: chunk c (16 kk rows, 4 KB) -> buf (0/1), 4 DMA instrs.
    //      source swizzled by involution f(o) = o ^ (((o>>8)&7)<<4). ----
    auto stage_chunk = [&](int c, int buf) {
        const char* gs = ktg + c * 4096;
        char* ld = reg + buf * 4096;
        #pragma unroll
        for (int i = 0; i < 4; ++i) {
            int key = ((i * 4 + (l >> 4)) & 7) << 4;
            int o = i * 1024 + l * 16;
            gload_lds16(gs + (o ^ key), ld + i * 1024);
        }
    };
    stage_chunk(0, 0);
    stage_chunk(1, 1);

    // ---- rb GEMM (in-register, overlaps kt DMA flight): d-range [0,64) ----
    f32x4 rbr[2][2];
    #pragma unroll
    for (int n = 0; n < 2; ++n)
        #pragma unroll
        for (int par = 0; par < 2; ++par) rbr[n][par] = f32x4{0.f, 0.f, 0.f, 0.f};
    #pragma unroll
    for (int par = 0; par < 2; ++par) {
        #pragma unroll
        for (int s = 0; s < 2; ++s) {
            short8 re = cvt8(row_emb + (size_t)(par * 16 + ln - I + 31) * 64
                                     + s * 32 + h * 8);
            rbr[0][par] = mfma16(re, q0[s], rbr[0][par]);
            rbr[1][par] = mfma16(re, q1[s], rbr[1][par]);
        }
    }

    // ---- phase 1: S^T = K Q^T, software-pipelined over 8 chunks ----
    f32x4 acc[2][8];
    #pragma unroll
    for (int n = 0; n < 2; ++n)
        #pragma unroll
        for (int t = 0; t < 8; ++t) acc[n][t] = f32x4{0.f, 0.f, 0.f, 0.f};
    int xk = (ln & 7) << 4;
    #pragma unroll
    for (int c = 0; c < 8; ++c) {
        if (c < 7) asm volatile("s_waitcnt vmcnt(4)" ::: "memory");
        else       asm volatile("s_waitcnt vmcnt(0)" ::: "memory");
        const char* cb = reg + (c & 1) * 4096;
        short8 kf[4];
        #pragma unroll
        for (int s = 0; s < 4; ++s)
            kf[s] = *(const short8*)(cb + ((ln * 256 + s * 64 + h * 16) ^ xk));
        asm volatile("s_waitcnt lgkmcnt(0)" ::: "memory");
        __builtin_amdgcn_sched_barrier(0);
        if (c + 2 < 8) stage_chunk(c + 2, c & 1);
        #pragma unroll
        for (int s = 0; s < 4; ++s) {
            acc[0][c] = mfma16(kf[s], q0[s], acc[0][c]);
            acc[1][c] = mfma16(kf[s], q1[s], acc[1][c]);
        }
    }

    // ---- bias + exp2 + partial row-sum + P~ store into own region ----
    // P~ layout: row J (256 B pitch), kk-local, phys = logical ^ ((J&7)<<4).
    #pragma unroll
    for (int n = 0; n < 2; ++n) {
        int J = n * 16 + ln;
        float sum = 0.f;
        #pragma unroll
        for (int t = 0; t < 8; ++t) {
            float cbv = cbr[n][t >> 1];
            float p0 = exp2f(acc[n][t][0] + rbr[n][t & 1][0] + cbv);
            float p1 = exp2f(acc[n][t][1] + rbr[n][t & 1][1] + cbv);
            float p2 = exp2f(acc[n][t][2] + rbr[n][t & 1][2] + cbv);
            float p3 = exp2f(acc[n][t][3] + rbr[n][t & 1][3] + cbv);
            sum += (p0 + p1) + (p2 + p3);
            *(uint2*)(reg + ((J * 256 + t * 32 + h * 8) ^ xk)) =
                make_uint2(cvtpk(p0, p1), cvtpk(p2, p3));
        }
        sum += __shfl_xor(sum, 16);
        sum += __shfl_xor(sum, 32);
        if (l < 16) wred[w * 32 + J] = sum;
    }
    __syncthreads();   // the ONLY barrier: all P~ slices + wred complete

    // ---- per-thread row sums (broadcast f32x4 LDS reads) ----
    f32x4 sum0 = f32x4{0.f, 0.f, 0.f, 0.f};
    f32x4 sum1 = f32x4{0.f, 0.f, 0.f, 0.f};
    #pragma unroll
    for (int w2 = 0; w2 < 8; ++w2) {
        sum0 += *(const f32x4*)&wred[w2 * 32 + h * 4];
        sum1 += *(const f32x4*)&wred[w2 * 32 + 16 + h * 4];
    }
    int j = tid >> 4;
    float sd = 0.f;
    #pragma unroll
    for (int w2 = 0; w2 < 8; ++w2) sd += wred[w2 * 32 + j];
    float invd = 1.0f / sd;

    // ---- PV: ctx = P~ @ X  (wave w -> d-span w*16), starts right at barrier ----
    f32x4 cacc[2] = {f32x4{0,0,0,0}, f32x4{0,0,0,0}};
    #pragma unroll
    for (int ks = 0; ks < 32; ++ks) {
        short8 xf8 = *(const short8*)(xb + ks * 32);
        #pragma unroll
        for (int m = 0; m < 2; ++m) {
            short8 pa = *(const short8*)(KT + (ks >> 2) * 8192 +
                (((m * 16 + ln) * 256 + (ks & 3) * 64 + h * 16) ^ xk));
            cacc[m] = mfma16(pa, xf8, cacc[m]);
        }
    }
    #pragma unroll
    for (int m = 0; m < 2; ++m)
        #pragma unroll
        for (int r = 0; r < 4; ++r) {
            int J = m * 16 + h * 4 + r;
            float inv = 1.0f / (m ? sum1[r] : sum0[r]);
            ctx_bf[((size_t)(b * 32 + J) * 32 + I) * 1024 + head * 128 + d0 + ln] =
                f2bf(cacc[m][r] * inv);
        }

    // ---- probs drain from LDS, coalesced, in the kernel TAIL ----
    {
        float* prow = probs + ((((size_t)(b * 32 + j) * 32 + I) * 8 + head) << 10);
        int jx = (j & 7) << 4;
        #pragma unroll
        for (int i = 0; i < 8; ++i) {
            int kk = i * 128 + (tid & 15) * 8;
            short8 pv = *(const short8*)(KT + i * 8192 +
                            ((j * 256 + (tid & 15) * 16) ^ jx));
            float4 o0, o1;
            o0.x = sbf2f(pv[0]) * invd; o0.y = sbf2f(pv[1]) * invd;
            o0.z = sbf2f(pv[2]) * invd; o0.w = sbf2f(pv[3]) * invd;
            o1.x = sbf2f(pv[4]) * invd; o1.y = sbf2f(pv[5]) * invd;
            o1.z = sbf2f(pv[6]) * invd; o1.w = sbf2f(pv[7]) * invd;
            *(float4*)(prow + kk)     = o0;
            *(float4*)(prow + kk + 4) = o1;
        }
    }
}

// ---------------- K7: output = ctx @ Wv^T + bv + x (MFMA) ----------------
__global__ __launch_bounds__(256) void k_out(const u16* __restrict__ ctx_bf,
    const u16* __restrict__ wv_bf, const float* __restrict__ bv,
    const float* __restrict__ xf, float* __restrict__ out)
{
    int tid = threadIdx.x;
    int w = tid >> 6, l = tid & 63, h = l >> 4, ln = l & 15;
    int wm = w >> 1, wn = w & 1;
    int t0 = blockIdx.x * 32 + wm * 16;
    int o0 = blockIdx.y * 64 + wn * 32;
    f32x4 acc[2] = {f32x4{0,0,0,0}, f32x4{0,0,0,0}};
    for (int ks = 0; ks < 32; ++ks) {
        short8 a = *(const short8*)(ctx_bf + (size_t)(t0 + ln) * 1024 + ks * 32 + h * 8);
        #pragma unroll
        for (int nt = 0; nt < 2; ++nt) {
            short8 bb = *(const short8*)(wv_bf + (size_t)(o0 + nt * 16 + ln) * 1024 + ks * 32 + h * 8);
            acc[nt] = mfma16(a, bb, acc[nt]);
        }
    }
    #pragma unroll
    for (int nt = 0; nt < 2; ++nt) {
        int o = o0 + nt * 16 + ln;
        float bvv = bv[o];
        #pragma unroll
        for (int r = 0; r < 4; ++r) {
            int t = t0 + h * 4 + r;
            out[(size_t)t * 128 + o] = acc[nt][r] + bvv + xf[(size_t)t * 128 + o];
        }
    }
}

extern "C" void kernel_launch(void* const* d_in, const int* in_sizes, int n_in,
                              void* d_out, int out_size, void* d_ws, size_t ws_size,
                              hipStream_t stream) {
    (void)in_sizes; (void)n_in; (void)out_size; (void)ws_size;
    const float* hs      = (const float*)d_in[0];
    const float* row_emb = (const float*)d_in[1];
    const float* col_emb = (const float*)d_in[2];
    const float* Wq      = (const float*)d_in[3];
    const float* Wk      = (const float*)d_in[4];
    const float* Wv      = (const float*)d_in[5];
    const float* bv      = (const float*)d_in[6];
    const float* ln_g    = (const float*)d_in[7];
    const float* ln_b    = (const float*)d_in[8];

    float* out   = (float*)d_out;
    float* probs = out + 1048576;

    char* ws = (char*)d_ws;
    float* xf     = (float*)(ws);                      //  4 MB
    u16*   xbf    = (u16*)(ws + 4194304);              //  2 MB
    u16*   q_bf   = (u16*)(ws + 6291456);              // 16 MB
    u16*   kt_bf  = (u16*)(ws + 23068672);             // 16 MB
    u16*   xt     = (u16*)(ws + 39845888);             //  2 MB
    u16*   wqk_bf = (u16*)(ws + 41943040);             // 512 KB
    u16*   wv_bf  = (u16*)(ws + 42467328);             // 256 KB
    u16*   ctx    = (u16*)(ws + 42729472);             // 16 MB
    float* cbias  = (float*)(ws + 59506688);           //  8 MB  (total 64.75 MB)

    k_init  <<<448, 256, 0, stream>>>(hs, ln_g, ln_b, Wq, Wk, Wv,
                                      xf, xbf, xt, wqk_bf, wv_bf);
    k_proj  <<<dim3(128, 32), 256, 0, stream>>>(xbf, wqk_bf, q_bf, kt_bf);
    k_cbias <<<2048, 256, 0, stream>>>(q_bf, col_emb, cbias);
    k_attn  <<<2048, 512, 0, stream>>>(q_bf, kt_bf, xt, row_emb, cbias, probs, ctx);
    k_out   <<<dim3(256, 2), 256, 0, stream>>>(ctx, wv_bf, bv, xf, out);
}

// Round 19
// 249.198 us; speedup vs baseline: 1.0864x; 1.0013x over previous
//
#include <hip/hip_runtime.h>
#include <hip/hip_bf16.h>

#define HEADS 8
#define D 128
// log2(e) / sqrt(128): q is pre-scaled by this so scores are in exp2 domain.
#define QSCALE 0.12751743f

typedef unsigned short u16;
typedef unsigned int u32;
typedef __attribute__((ext_vector_type(8))) short short8;
typedef __attribute__((ext_vector_type(4))) float f32x4;

static __device__ inline float sbf2f(short s) {
    return __uint_as_float(((u32)(unsigned short)s) << 16);
}
static __device__ inline u16 f2bf(float f) {
    u32 u = __float_as_uint(f);
    return (u16)((u + 0x7FFFu + ((u >> 16) & 1u)) >> 16);
}
static __device__ inline u32 pk2bf(float a, float b) {
    return (u32)f2bf(a) | ((u32)f2bf(b) << 16);
}
// hardware v_cvt_pk_bf16_f32 path
static __device__ inline u32 cvtpk(float a, float b) {
    union { __hip_bfloat162 h; u32 u; } x;
    x.h = __float22bfloat162_rn(make_float2(a, b));
    return x.u;
}
static __device__ inline f32x4 mfma16(short8 a, short8 b, f32x4 c) {
    return __builtin_amdgcn_mfma_f32_16x16x32_bf16(a, b, c, 0, 0, 0);
}
// load 8 consecutive f32 and convert to a bf16 MFMA fragment
static __device__ inline short8 cvt8(const float* e) {
    f32x4 v0 = *(const f32x4*)e;
    f32x4 v1 = *(const f32x4*)(e + 4);
    union { uint4 u; short8 s; } x;
    x.u = make_uint4(pk2bf(v0[0], v0[1]), pk2bf(v0[2], v0[3]),
                     pk2bf(v1[0], v1[1]), pk2bf(v1[2], v1[3]));
    return x.s;
}
// async global->LDS, 16B per lane. Dest = uniform base + lane*16 (HW rule).
static __device__ __forceinline__ void gload_lds16(const void* g, void* l) {
    __builtin_amdgcn_global_load_lds(
        (const __attribute__((address_space(1))) u32*)g,
        (__attribute__((address_space(3))) u32*)(u32)(uintptr_t)l,
        16, 0, 0);
}

// ---------------- K1: fused {Wq/Wk/Wv cvt} + {LayerNorm + transpose} ----------
// blocks 0..383: weight conversion; blocks 384..447: LN + xbf + xt.
__global__ __launch_bounds__(256) void k_init(const float* __restrict__ hs,
    const float* __restrict__ g, const float* __restrict__ bb,
    const float* __restrict__ Wq, const float* __restrict__ Wk,
    const float* __restrict__ Wv,
    float* __restrict__ xf, u16* __restrict__ xbf, u16* __restrict__ xt,
    u16* __restrict__ wqk, u16* __restrict__ wv)
{
    __shared__ __align__(16) u16 tl[128][136];
    int bid = blockIdx.x;
    int tid = threadIdx.x;
    if (bid < 384) {
        int idx = (bid * 256 + tid) * 4;   // 393216 floats total
        const float* src;
        u16* dst;
        if (idx < 131072)      { src = Wq + idx;            dst = wqk + idx; }
        else if (idx < 262144) { src = Wk + (idx - 131072); dst = wqk + idx; }
        else                   { src = Wv + (idx - 262144); dst = wv + (idx - 262144); }
        f32x4 v = *(const f32x4*)src;
        *(uint2*)dst = make_uint2(pk2bf(v[0], v[1]), pk2bf(v[2], v[3]));
        return;
    }
    int blk = bid - 384;
    int b = blk >> 3, ch = blk & 7;
    int c4 = (tid & 31) * 4;
    f32x4 g4 = *(const f32x4*)(g + c4);
    f32x4 b4 = *(const f32x4*)(bb + c4);
    const float* src = hs + ((size_t)b * 1024 + ch * 128) * 128;
    #pragma unroll
    for (int it = 0; it < 16; ++it) {
        int p = (tid >> 5) + it * 8;
        f32x4 v = *(const f32x4*)(src + (size_t)p * 128 + c4);
        float s1 = (v[0] + v[1]) + (v[2] + v[3]);
        float s2 = (v[0] * v[0] + v[1] * v[1]) + (v[2] * v[2] + v[3] * v[3]);
        #pragma unroll
        for (int off = 1; off < 32; off <<= 1) {
            s1 += __shfl_xor(s1, off);
            s2 += __shfl_xor(s2, off);
        }
        float mu  = s1 * 0.0078125f;
        float var = s2 * 0.0078125f - mu * mu;
        float inv = rsqrtf(var + 1e-5f);
        f32x4 o;
        #pragma unroll
        for (int q = 0; q < 4; ++q) o[q] = (v[q] - mu) * inv * g4[q] + b4[q];
        size_t row = (size_t)b * 1024 + ch * 128 + p;
        *(f32x4*)(xf + row * 128 + c4) = o;
        *(uint2*)(xbf + row * 128 + c4) = make_uint2(pk2bf(o[0], o[1]), pk2bf(o[2], o[3]));
        tl[c4 + 0][p] = f2bf(o[0]);
        tl[c4 + 1][p] = f2bf(o[1]);
        tl[c4 + 2][p] = f2bf(o[2]);
        tl[c4 + 3][p] = f2bf(o[3]);
    }
    __syncthreads();
    u16* dst = xt + (size_t)b * 131072 + ch * 128;
    #pragma unroll
    for (int i = 0; i < 8; ++i) {
        int d = (tid >> 4) + i * 16, c8 = (tid & 15) * 8;
        *(uint4*)(dst + (size_t)d * 1024 + c8) = *(const uint4*)&tl[d][c8];
    }
}

// ---------------- K2: Q/K projection (MFMA, swapped operands) ----------------
// A = weight rows (o), B = token rows -> C[row=o_local, col=token]: each lane
// owns token t0+ln and 4 CONSECUTIVE d per n-tile -> packed uint2 stores.
__global__ __launch_bounds__(256) void k_proj(const u16* __restrict__ xbf,
    const u16* __restrict__ wqk,
    u16* __restrict__ q_bf, u16* __restrict__ kt_bf)
{
    int tid = threadIdx.x;
    int w = tid >> 6, l = tid & 63, h = l >> 4, ln = l & 15;
    int t0 = blockIdx.x * 64 + w * 16;
    int o0 = blockIdx.y * 64;
    short8 tb[4];
    #pragma unroll
    for (int s = 0; s < 4; ++s)
        tb[s] = *(const short8*)(xbf + (size_t)(t0 + ln) * 128 + s * 32 + h * 8);
    f32x4 acc[4];
    #pragma unroll
    for (int n = 0; n < 4; ++n) acc[n] = f32x4{0.f, 0.f, 0.f, 0.f};
    #pragma unroll
    for (int n = 0; n < 4; ++n) {
        const u16* wsrc = wqk + (size_t)(o0 + n * 16 + ln) * 128;
        #pragma unroll
        for (int s = 0; s < 4; ++s) {
            short8 wf = *(const short8*)(wsrc + s * 32 + h * 8);
            acc[n] = mfma16(wf, tb[s], acc[n]);   // A=weights, B=tokens
        }
    }
    bool isq = (o0 < 1024);
    float os = isq ? QSCALE : 1.0f;
    int head = (o0 & 1023) >> 7;
    int od = (o0 & 127);
    u16* basep = isq ? q_bf : kt_bf;
    int t = t0 + ln;
    int b = t >> 10, pos = t & 1023;
    size_t row;
    if (isq) row = (size_t)(b * 8 + head) * 1024 + pos;
    else { int I = pos >> 5, J = pos & 31; row = (size_t)(b * 8 + head) * 1024 + (J * 32 + I); }
    u16* dst = basep + row * 128 + od + h * 4;
    #pragma unroll
    for (int n = 0; n < 4; ++n) {
        *(uint2*)(dst + n * 16) = make_uint2(
            pk2bf(acc[n][0] * os, acc[n][1] * os),
            pk2bf(acc[n][2] * os, acc[n][3] * os));
    }
}

// ---------------- K3: bias GEMMs -> rbias[J][K], cbias[J][L] (pre-gathered) ----
__global__ __launch_bounds__(256) void k_bias(const u16* __restrict__ q_bf,
    const float* __restrict__ row_emb, const float* __restrict__ col_emb,
    float* __restrict__ rbias, float* __restrict__ cbias)
{
    __shared__ __align__(16) float cbf[32][68];
    int tid = threadIdx.x;
    int w = tid >> 6, l = tid & 63, h = l >> 4, ln = l & 15;
    int blk = blockIdx.x;
    int bh = blk >> 5, I = blk & 31;
    const u16* qb = q_bf + ((size_t)bh * 1024 + I * 32) * 128;
    size_t obase = (size_t)blk * 1024;
    if (w < 2) {
        short8 a0 = *(const short8*)(qb + (size_t)(w * 16 + ln) * 128 + h * 8);
        short8 a1 = *(const short8*)(qb + (size_t)(w * 16 + ln) * 128 + 32 + h * 8);
        f32x4 o[2] = {f32x4{0,0,0,0}, f32x4{0,0,0,0}};
        #pragma unroll
        for (int n = 0; n < 2; ++n) {
            int K = n * 16 + ln;
            const float* e = row_emb + (size_t)(K - I + 31) * 64 + h * 8;
            o[n] = mfma16(a0, cvt8(e), o[n]);
            o[n] = mfma16(a1, cvt8(e + 32), o[n]);
        }
        #pragma unroll
        for (int n = 0; n < 2; ++n)
            #pragma unroll
            for (int r = 0; r < 4; ++r)
                rbias[obase + (size_t)(w * 16 + h * 4 + r) * 32 + n * 16 + ln] = o[n][r];
    } else {
        int m = w - 2;
        short8 a0 = *(const short8*)(qb + (size_t)(m * 16 + ln) * 128 + 64 + h * 8);
        short8 a1 = *(const short8*)(qb + (size_t)(m * 16 + ln) * 128 + 96 + h * 8);
        f32x4 o[4] = {f32x4{0,0,0,0}, f32x4{0,0,0,0}, f32x4{0,0,0,0}, f32x4{0,0,0,0}};
        #pragma unroll
        for (int n = 0; n < 4; ++n) {
            int p = n * 16 + ln;
            if (p > 62) p = 62;            // clamp: p=63 never consumed
            const float* e = col_emb + (size_t)p * 64 + h * 8;
            o[n] = mfma16(a0, cvt8(e), o[n]);
            o[n] = mfma16(a1, cvt8(e + 32), o[n]);
        }
        #pragma unroll
        for (int n = 0; n < 4; ++n)
            #pragma unroll
            for (int r = 0; r < 4; ++r)
                cbf[m * 16 + h * 4 + r][n * 16 + ln] = o[n][r];
    }
    __syncthreads();
    int J = tid >> 3, L0 = (tid & 7) * 4;
    float4 g;
    g.x = cbf[J][L0 + 0 - J + 31];
    g.y = cbf[J][L0 + 1 - J + 31];
    g.z = cbf[J][L0 + 2 - J + 31];
    g.w = cbf[J][L0 + 3 - J + 31];
    *(float4*)(cbias + obase + (size_t)J * 32 + L0) = g;
}

// ---------------- K4: fused scores + softmax + PV (async kt staging) ----------
// R19 k_attn = R16 verbatim (measured best: 162.5 us). rbias/cbias from
// buffers; no setprio (R17: -6 us); no in-kernel rb-GEMM (R18: -7 us);
// probs drain in kernel tail.
__global__ __launch_bounds__(512, 4) void k_attn(const u16* __restrict__ q_bf,
    const u16* __restrict__ kt_bf, const u16* __restrict__ xt_bf,
    const float* __restrict__ rbias, const float* __restrict__ cbias,
    float* __restrict__ probs, u16* __restrict__ ctx_bf)
{
    __shared__ __align__(16) char KT[8 * 8192];   // per-wave 8 KB: kt chunks, then P~
    __shared__ float wred[256];                   // partial sums [w*32 + J]

    int tid = threadIdx.x;
    int w = tid >> 6, l = tid & 63, h = l >> 4, ln = l & 15;
    int flat = blockIdx.x;
    int bh = flat >> 5, I = flat & 31;
    int b = bh >> 3, head = bh & 7;
    int kk0 = w * 128;
    char* reg = KT + w * 8192;
    const char* ktg = (const char*)(kt_bf + ((size_t)bh * 1024 + kk0) * 128);  // 32 KB span
    int d0 = w * 16;
    const u16* xb = xt_bf + (size_t)b * 131072 + (size_t)(d0 + ln) * 1024 + h * 8;

    // ---- prologue VMEM (retire before chunk0 consumed): bias + q ----
    const float* rbase = rbias + (size_t)(bh * 32 + I) * 1024;
    const float* cbase = cbias + (size_t)(bh * 32 + I) * 1024;
    f32x4 rbr[2][2], cbr[2];
    #pragma unroll
    for (int n = 0; n < 2; ++n) {
        int J = n * 16 + ln;
        rbr[n][0] = *(const f32x4*)(rbase + J * 32 + h * 4);
        rbr[n][1] = *(const f32x4*)(rbase + J * 32 + 16 + h * 4);
        cbr[n]    = *(const f32x4*)(cbase + J * 32 + w * 4);
    }
    const u16* qbase = q_bf + ((size_t)bh * 1024 + I * 32) * 128;
    short8 q0[4], q1[4];
    #pragma unroll
    for (int s = 0; s < 4; ++s) {
        q0[s] = *(const short8*)(qbase + (size_t)ln * 128 + s * 32 + h * 8);
        q1[s] = *(const short8*)(qbase + (size_t)(16 + ln) * 128 + s * 32 + h * 8);
    }

    // ---- stage helper: chunk c (16 kk rows, 4 KB) -> buf (0/1), 4 DMA instrs.
    //      source swizzled by involution f(o) = o ^ (((o>>8)&7)<<4). ----
    auto stage_chunk = [&](int c, int buf) {
        const char* gs = ktg + c * 4096;
        char* ld = reg + buf * 4096;
        #pragma unroll
        for (int i = 0; i < 4; ++i) {
            int key = ((i * 4 + (l >> 4)) & 7) << 4;
            int o = i * 1024 + l * 16;
            gload_lds16(gs + (o ^ key), ld + i * 1024);
        }
    };
    stage_chunk(0, 0);
    stage_chunk(1, 1);

    // ---- phase 1: S^T = K Q^T, software-pipelined over 8 chunks ----
    f32x4 acc[2][8];
    #pragma unroll
    for (int n = 0; n < 2; ++n)
        #pragma unroll
        for (int t = 0; t < 8; ++t) acc[n][t] = f32x4{0.f, 0.f, 0.f, 0.f};
    int xk = (ln & 7) << 4;
    #pragma unroll
    for (int c = 0; c < 8; ++c) {
        if (c < 7) asm volatile("s_waitcnt vmcnt(4)" ::: "memory");
        else       asm volatile("s_waitcnt vmcnt(0)" ::: "memory");
        const char* cb = reg + (c & 1) * 4096;
        short8 kf[4];
        #pragma unroll
        for (int s = 0; s < 4; ++s)
            kf[s] = *(const short8*)(cb + ((ln * 256 + s * 64 + h * 16) ^ xk));
        asm volatile("s_waitcnt lgkmcnt(0)" ::: "memory");
        __builtin_amdgcn_sched_barrier(0);
        if (c + 2 < 8) stage_chunk(c + 2, c & 1);
        #pragma unroll
        for (int s = 0; s < 4; ++s) {
            acc[0][c] = mfma16(kf[s], q0[s], acc[0][c]);
            acc[1][c] = mfma16(kf[s], q1[s], acc[1][c]);
        }
    }

    // ---- bias + exp2 + partial row-sum + P~ store into own region ----
    // P~ layout: row J (256 B pitch), kk-local, phys = logical ^ ((J&7)<<4).
    #pragma unroll
    for (int n = 0; n < 2; ++n) {
        int J = n * 16 + ln;
        float sum = 0.f;
        #pragma unroll
        for (int t = 0; t < 8; ++t) {
            float cbv = cbr[n][t >> 1];
            float p0 = exp2f(acc[n][t][0] + rbr[n][t & 1][0] + cbv);
            float p1 = exp2f(acc[n][t][1] + rbr[n][t & 1][1] + cbv);
            float p2 = exp2f(acc[n][t][2] + rbr[n][t & 1][2] + cbv);
            float p3 = exp2f(acc[n][t][3] + rbr[n][t & 1][3] + cbv);
            sum += (p0 + p1) + (p2 + p3);
            *(uint2*)(reg + ((J * 256 + t * 32 + h * 8) ^ xk)) =
                make_uint2(cvtpk(p0, p1), cvtpk(p2, p3));
        }
        sum += __shfl_xor(sum, 16);
        sum += __shfl_xor(sum, 32);
        if (l < 16) wred[w * 32 + J] = sum;
    }
    __syncthreads();   // the ONLY barrier: all P~ slices + wred complete

    // ---- per-thread row sums (broadcast f32x4 LDS reads) ----
    f32x4 sum0 = f32x4{0.f, 0.f, 0.f, 0.f};
    f32x4 sum1 = f32x4{0.f, 0.f, 0.f, 0.f};
    #pragma unroll
    for (int w2 = 0; w2 < 8; ++w2) {
        sum0 += *(const f32x4*)&wred[w2 * 32 + h * 4];
        sum1 += *(const f32x4*)&wred[w2 * 32 + 16 + h * 4];
    }
    int j = tid >> 4;
    float sd = 0.f;
    #pragma unroll
    for (int w2 = 0; w2 < 8; ++w2) sd += wred[w2 * 32 + j];
    float invd = 1.0f / sd;

    // ---- PV: ctx = P~ @ X  (wave w -> d-span w*16), starts right at barrier ----
    f32x4 cacc[2] = {f32x4{0,0,0,0}, f32x4{0,0,0,0}};
    #pragma unroll
    for (int ks = 0; ks < 32; ++ks) {
        short8 xf8 = *(const short8*)(xb + ks * 32);
        #pragma unroll
        for (int m = 0; m < 2; ++m) {
            short8 pa = *(const short8*)(KT + (ks >> 2) * 8192 +
                (((m * 16 + ln) * 256 + (ks & 3) * 64 + h * 16) ^ xk));
            cacc[m] = mfma16(pa, xf8, cacc[m]);
        }
    }
    #pragma unroll
    for (int m = 0; m < 2; ++m)
        #pragma unroll
        for (int r = 0; r < 4; ++r) {
            int J = m * 16 + h * 4 + r;
            float inv = 1.0f / (m ? sum1[r] : sum0[r]);
            ctx_bf[((size_t)(b * 32 + J) * 32 + I) * 1024 + head * 128 + d0 + ln] =
                f2bf(cacc[m][r] * inv);
        }

    // ---- probs drain from LDS, coalesced, in the kernel TAIL (overlaps the
    //      next block's kt staging; PV doesn't wait behind these ds_reads) ----
    {
        float* prow = probs + ((((size_t)(b * 32 + j) * 32 + I) * 8 + head) << 10);
        int jx = (j & 7) << 4;
        #pragma unroll
        for (int i = 0; i < 8; ++i) {
            int kk = i * 128 + (tid & 15) * 8;
            short8 pv = *(const short8*)(KT + i * 8192 +
                            ((j * 256 + (tid & 15) * 16) ^ jx));
            float4 o0, o1;
            o0.x = sbf2f(pv[0]) * invd; o0.y = sbf2f(pv[1]) * invd;
            o0.z = sbf2f(pv[2]) * invd; o0.w = sbf2f(pv[3]) * invd;
            o1.x = sbf2f(pv[4]) * invd; o1.y = sbf2f(pv[5]) * invd;
            o1.z = sbf2f(pv[6]) * invd; o1.w = sbf2f(pv[7]) * invd;
            *(float4*)(prow + kk)     = o0;
            *(float4*)(prow + kk + 4) = o1;
        }
    }
}

// ---------------- K7: output = ctx @ Wv^T + bv + x (MFMA) ----------------
__global__ __launch_bounds__(256) void k_out(const u16* __restrict__ ctx_bf,
    const u16* __restrict__ wv_bf, const float* __restrict__ bv,
    const float* __restrict__ xf, float* __restrict__ out)
{
    int tid = threadIdx.x;
    int w = tid >> 6, l = tid & 63, h = l >> 4, ln = l & 15;
    int wm = w >> 1, wn = w & 1;
    int t0 = blockIdx.x * 32 + wm * 16;
    int o0 = blockIdx.y * 64 + wn * 32;
    f32x4 acc[2] = {f32x4{0,0,0,0}, f32x4{0,0,0,0}};
    for (int ks = 0; ks < 32; ++ks) {
        short8 a = *(const short8*)(ctx_bf + (size_t)(t0 + ln) * 1024 + ks * 32 + h * 8);
        #pragma unroll
        for (int nt = 0; nt < 2; ++nt) {
            short8 bb = *(const short8*)(wv_bf + (size_t)(o0 + nt * 16 + ln) * 1024 + ks * 32 + h * 8);
            acc[nt] = mfma16(a, bb, acc[nt]);
        }
    }
    #pragma unroll
    for (int nt = 0; nt < 2; ++nt) {
        int o = o0 + nt * 16 + ln;
        float bvv = bv[o];
        #pragma unroll
        for (int r = 0; r < 4; ++r) {
            int t = t0 + h * 4 + r;
            out[(size_t)t * 128 + o] = acc[nt][r] + bvv + xf[(size_t)t * 128 + o];
        }
    }
}

extern "C" void kernel_launch(void* const* d_in, const int* in_sizes, int n_in,
                              void* d_out, int out_size, void* d_ws, size_t ws_size,
                              hipStream_t stream) {
    (void)in_sizes; (void)n_in; (void)out_size; (void)ws_size;
    const float* hs      = (const float*)d_in[0];
    const float* row_emb = (const float*)d_in[1];
    const float* col_emb = (const float*)d_in[2];
    const float* Wq      = (const float*)d_in[3];
    const float* Wk      = (const float*)d_in[4];
    const float* Wv      = (const float*)d_in[5];
    const float* bv      = (const float*)d_in[6];
    const float* ln_g    = (const float*)d_in[7];
    const float* ln_b    = (const float*)d_in[8];

    float* out   = (float*)d_out;
    float* probs = out + 1048576;

    char* ws = (char*)d_ws;
    float* xf     = (float*)(ws);                      //  4 MB
    u16*   xbf    = (u16*)(ws + 4194304);              //  2 MB
    u16*   q_bf   = (u16*)(ws + 6291456);              // 16 MB
    u16*   kt_bf  = (u16*)(ws + 23068672);             // 16 MB
    u16*   xt     = (u16*)(ws + 39845888);             //  2 MB
    u16*   wqk_bf = (u16*)(ws + 41943040);             // 512 KB
    u16*   wv_bf  = (u16*)(ws + 42467328);             // 256 KB
    u16*   ctx    = (u16*)(ws + 42729472);             // 16 MB
    float* rbias  = (float*)(ws + 59506688);           //  8 MB
    float* cbias  = (float*)(ws + 67895296);           //  8 MB  (total 72.75 MB)

    k_init <<<448, 256, 0, stream>>>(hs, ln_g, ln_b, Wq, Wk, Wv,
                                     xf, xbf, xt, wqk_bf, wv_bf);
    k_proj <<<dim3(128, 32), 256, 0, stream>>>(xbf, wqk_bf, q_bf, kt_bf);
    k_bias <<<2048, 256, 0, stream>>>(q_bf, row_emb, col_emb, rbias, cbias);
    k_attn <<<2048, 512, 0, stream>>>(q_bf, kt_bf, xt, rbias, cbias, probs, ctx);
    k_out  <<<dim3(256, 2), 256, 0, stream>>>(ctx, wv_bf, bv, xf, out);
}

// Round 20
// 228.269 us; speedup vs baseline: 1.1860x; 1.0917x over previous
//
#include <hip/hip_runtime.h>
#include <hip/hip_bf16.h>

#define HEADS 8
#define D 128
// log2(e) / sqrt(128): q is pre-scaled by this so scores are in exp2 domain.
#define QSCALE 0.12751743f

typedef unsigned short u16;
typedef unsigned int u32;
typedef __attribute__((ext_vector_type(8))) short short8;
typedef __attribute__((ext_vector_type(4))) float f32x4;

static __device__ inline float sbf2f(short s) {
    return __uint_as_float(((u32)(unsigned short)s) << 16);
}
static __device__ inline u16 f2bf(float f) {
    u32 u = __float_as_uint(f);
    return (u16)((u + 0x7FFFu + ((u >> 16) & 1u)) >> 16);
}
static __device__ inline u32 pk2bf(float a, float b) {
    return (u32)f2bf(a) | ((u32)f2bf(b) << 16);
}
// hardware v_cvt_pk_bf16_f32 path
static __device__ inline u32 cvtpk(float a, float b) {
    union { __hip_bfloat162 h; u32 u; } x;
    x.h = __float22bfloat162_rn(make_float2(a, b));
    return x.u;
}
static __device__ inline f32x4 mfma16(short8 a, short8 b, f32x4 c) {
    return __builtin_amdgcn_mfma_f32_16x16x32_bf16(a, b, c, 0, 0, 0);
}
// load 8 consecutive f32 and convert to a bf16 MFMA fragment
static __device__ inline short8 cvt8(const float* e) {
    f32x4 v0 = *(const f32x4*)e;
    f32x4 v1 = *(const f32x4*)(e + 4);
    union { uint4 u; short8 s; } x;
    x.u = make_uint4(pk2bf(v0[0], v0[1]), pk2bf(v0[2], v0[3]),
                     pk2bf(v1[0], v1[1]), pk2bf(v1[2], v1[3]));
    return x.s;
}
// async global->LDS, 16B per lane. Dest = uniform base + lane*16 (HW rule).
static __device__ __forceinline__ void gload_lds16(const void* g, void* l) {
    __builtin_amdgcn_global_load_lds(
        (const __attribute__((address_space(1))) u32*)g,
        (__attribute__((address_space(3))) u32*)(u32)(uintptr_t)l,
        16, 0, 0);
}

// ---------------- K1: fused {Wq/Wk/Wv cvt} + {LayerNorm + transpose} ----------
// blocks 0..383: weight conversion; blocks 384..447: LN + xbf + xt.
// xt layout (NEW): kk-panel tiles -- element (d, kk) at u16 address
//   b*131072 + ((kk>>5)*128 + d)*32 + (kk&31)
// so PV's per-instruction fragment reads are 1 KB contiguous per wave.
__global__ __launch_bounds__(256) void k_init(const float* __restrict__ hs,
    const float* __restrict__ g, const float* __restrict__ bb,
    const float* __restrict__ Wq, const float* __restrict__ Wk,
    const float* __restrict__ Wv,
    float* __restrict__ xf, u16* __restrict__ xbf, u16* __restrict__ xt,
    u16* __restrict__ wqk, u16* __restrict__ wv)
{
    __shared__ __align__(16) u16 tl[128][136];
    int bid = blockIdx.x;
    int tid = threadIdx.x;
    if (bid < 384) {
        int idx = (bid * 256 + tid) * 4;   // 393216 floats total
        const float* src;
        u16* dst;
        if (idx < 131072)      { src = Wq + idx;            dst = wqk + idx; }
        else if (idx < 262144) { src = Wk + (idx - 131072); dst = wqk + idx; }
        else                   { src = Wv + (idx - 262144); dst = wv + (idx - 262144); }
        f32x4 v = *(const f32x4*)src;
        *(uint2*)dst = make_uint2(pk2bf(v[0], v[1]), pk2bf(v[2], v[3]));
        return;
    }
    int blk = bid - 384;
    int b = blk >> 3, ch = blk & 7;
    int c4 = (tid & 31) * 4;
    f32x4 g4 = *(const f32x4*)(g + c4);
    f32x4 b4 = *(const f32x4*)(bb + c4);
    const float* src = hs + ((size_t)b * 1024 + ch * 128) * 128;
    #pragma unroll
    for (int it = 0; it < 16; ++it) {
        int p = (tid >> 5) + it * 8;
        f32x4 v = *(const f32x4*)(src + (size_t)p * 128 + c4);
        float s1 = (v[0] + v[1]) + (v[2] + v[3]);
        float s2 = (v[0] * v[0] + v[1] * v[1]) + (v[2] * v[2] + v[3] * v[3]);
        #pragma unroll
        for (int off = 1; off < 32; off <<= 1) {
            s1 += __shfl_xor(s1, off);
            s2 += __shfl_xor(s2, off);
        }
        float mu  = s1 * 0.0078125f;
        float var = s2 * 0.0078125f - mu * mu;
        float inv = rsqrtf(var + 1e-5f);
        f32x4 o;
        #pragma unroll
        for (int q = 0; q < 4; ++q) o[q] = (v[q] - mu) * inv * g4[q] + b4[q];
        size_t row = (size_t)b * 1024 + ch * 128 + p;
        *(f32x4*)(xf + row * 128 + c4) = o;
        *(uint2*)(xbf + row * 128 + c4) = make_uint2(pk2bf(o[0], o[1]), pk2bf(o[2], o[3]));
        tl[c4 + 0][p] = f2bf(o[0]);
        tl[c4 + 1][p] = f2bf(o[1]);
        tl[c4 + 2][p] = f2bf(o[2]);
        tl[c4 + 3][p] = f2bf(o[3]);
    }
    __syncthreads();
    u16* dst = xt + (size_t)b * 131072;
    #pragma unroll
    for (int i = 0; i < 8; ++i) {
        int d = (tid >> 4) + i * 16, c8 = (tid & 15) * 8;
        int kk = ch * 128 + c8;
        *(uint4*)(dst + ((size_t)(kk >> 5) * 128 + d) * 32 + (kk & 31)) =
            *(const uint4*)&tl[d][c8];
    }
}

// ---------------- K2: Q/K projection (MFMA, swapped operands) ----------------
// A = weight rows (o), B = token rows -> C[row=o_local, col=token]: each lane
// owns token t0+ln and 4 CONSECUTIVE d per n-tile -> packed uint2 stores.
__global__ __launch_bounds__(256) void k_proj(const u16* __restrict__ xbf,
    const u16* __restrict__ wqk,
    u16* __restrict__ q_bf, u16* __restrict__ kt_bf)
{
    int tid = threadIdx.x;
    int w = tid >> 6, l = tid & 63, h = l >> 4, ln = l & 15;
    int t0 = blockIdx.x * 64 + w * 16;
    int o0 = blockIdx.y * 64;
    short8 tb[4];
    #pragma unroll
    for (int s = 0; s < 4; ++s)
        tb[s] = *(const short8*)(xbf + (size_t)(t0 + ln) * 128 + s * 32 + h * 8);
    f32x4 acc[4];
    #pragma unroll
    for (int n = 0; n < 4; ++n) acc[n] = f32x4{0.f, 0.f, 0.f, 0.f};
    #pragma unroll
    for (int n = 0; n < 4; ++n) {
        const u16* wsrc = wqk + (size_t)(o0 + n * 16 + ln) * 128;
        #pragma unroll
        for (int s = 0; s < 4; ++s) {
            short8 wf = *(const short8*)(wsrc + s * 32 + h * 8);
            acc[n] = mfma16(wf, tb[s], acc[n]);   // A=weights, B=tokens
        }
    }
    bool isq = (o0 < 1024);
    float os = isq ? QSCALE : 1.0f;
    int head = (o0 & 1023) >> 7;
    int od = (o0 & 127);
    u16* basep = isq ? q_bf : kt_bf;
    int t = t0 + ln;
    int b = t >> 10, pos = t & 1023;
    size_t row;
    if (isq) row = (size_t)(b * 8 + head) * 1024 + pos;
    else { int I = pos >> 5, J = pos & 31; row = (size_t)(b * 8 + head) * 1024 + (J * 32 + I); }
    u16* dst = basep + row * 128 + od + h * 4;
    #pragma unroll
    for (int n = 0; n < 4; ++n) {
        *(uint2*)(dst + n * 16) = make_uint2(
            pk2bf(acc[n][0] * os, acc[n][1] * os),
            pk2bf(acc[n][2] * os, acc[n][3] * os));
    }
}

// ---------------- K3: bias GEMMs -> rbias[J][K], cbias[J][L] (pre-gathered) ----
__global__ __launch_bounds__(256) void k_bias(const u16* __restrict__ q_bf,
    const float* __restrict__ row_emb, const float* __restrict__ col_emb,
    float* __restrict__ rbias, float* __restrict__ cbias)
{
    __shared__ __align__(16) float cbf[32][68];
    int tid = threadIdx.x;
    int w = tid >> 6, l = tid & 63, h = l >> 4, ln = l & 15;
    int blk = blockIdx.x;
    int bh = blk >> 5, I = blk & 31;
    const u16* qb = q_bf + ((size_t)bh * 1024 + I * 32) * 128;
    size_t obase = (size_t)blk * 1024;
    if (w < 2) {
        short8 a0 = *(const short8*)(qb + (size_t)(w * 16 + ln) * 128 + h * 8);
        short8 a1 = *(const short8*)(qb + (size_t)(w * 16 + ln) * 128 + 32 + h * 8);
        f32x4 o[2] = {f32x4{0,0,0,0}, f32x4{0,0,0,0}};
        #pragma unroll
        for (int n = 0; n < 2; ++n) {
            int K = n * 16 + ln;
            const float* e = row_emb + (size_t)(K - I + 31) * 64 + h * 8;
            o[n] = mfma16(a0, cvt8(e), o[n]);
            o[n] = mfma16(a1, cvt8(e + 32), o[n]);
        }
        #pragma unroll
        for (int n = 0; n < 2; ++n)
            #pragma unroll
            for (int r = 0; r < 4; ++r)
                rbias[obase + (size_t)(w * 16 + h * 4 + r) * 32 + n * 16 + ln] = o[n][r];
    } else {
        int m = w - 2;
        short8 a0 = *(const short8*)(qb + (size_t)(m * 16 + ln) * 128 + 64 + h * 8);
        short8 a1 = *(const short8*)(qb + (size_t)(m * 16 + ln) * 128 + 96 + h * 8);
        f32x4 o[4] = {f32x4{0,0,0,0}, f32x4{0,0,0,0}, f32x4{0,0,0,0}, f32x4{0,0,0,0}};
        #pragma unroll
        for (int n = 0; n < 4; ++n) {
            int p = n * 16 + ln;
            if (p > 62) p = 62;            // clamp: p=63 never consumed
            const float* e = col_emb + (size_t)p * 64 + h * 8;
            o[n] = mfma16(a0, cvt8(e), o[n]);
            o[n] = mfma16(a1, cvt8(e + 32), o[n]);
        }
        #pragma unroll
        for (int n = 0; n < 4; ++n)
            #pragma unroll
            for (int r = 0; r < 4; ++r)
                cbf[m * 16 + h * 4 + r][n * 16 + ln] = o[n][r];
    }
    __syncthreads();
    int J = tid >> 3, L0 = (tid & 7) * 4;
    float4 g;
    g.x = cbf[J][L0 + 0 - J + 31];
    g.y = cbf[J][L0 + 1 - J + 31];
    g.z = cbf[J][L0 + 2 - J + 31];
    g.w = cbf[J][L0 + 3 - J + 31];
    *(float4*)(cbias + obase + (size_t)J * 32 + L0) = g;
}

// ---------------- K4: fused scores + softmax + PV (async kt staging) ----------
// R20 = R19 + kk-panel xt layout: PV fragment loads are 1 KB contiguous per
// wave-instruction (was 16 scattered 16B sectors) -- the last scattered access.
__global__ __launch_bounds__(512, 4) void k_attn(const u16* __restrict__ q_bf,
    const u16* __restrict__ kt_bf, const u16* __restrict__ xt_bf,
    const float* __restrict__ rbias, const float* __restrict__ cbias,
    float* __restrict__ probs, u16* __restrict__ ctx_bf)
{
    __shared__ __align__(16) char KT[8 * 8192];   // per-wave 8 KB: kt chunks, then P~
    __shared__ float wred[256];                   // partial sums [w*32 + J]

    int tid = threadIdx.x;
    int w = tid >> 6, l = tid & 63, h = l >> 4, ln = l & 15;
    int flat = blockIdx.x;
    int bh = flat >> 5, I = flat & 31;
    int b = bh >> 3, head = bh & 7;
    int kk0 = w * 128;
    char* reg = KT + w * 8192;
    const char* ktg = (const char*)(kt_bf + ((size_t)bh * 1024 + kk0) * 128);  // 32 KB span
    int d0 = w * 16;
    const u16* xtb = xt_bf + (size_t)b * 131072;

    // ---- prologue VMEM (retire before chunk0 consumed): bias + q ----
    const float* rbase = rbias + (size_t)(bh * 32 + I) * 1024;
    const float* cbase = cbias + (size_t)(bh * 32 + I) * 1024;
    f32x4 rbr[2][2], cbr[2];
    #pragma unroll
    for (int n = 0; n < 2; ++n) {
        int J = n * 16 + ln;
        rbr[n][0] = *(const f32x4*)(rbase + J * 32 + h * 4);
        rbr[n][1] = *(const f32x4*)(rbase + J * 32 + 16 + h * 4);
        cbr[n]    = *(const f32x4*)(cbase + J * 32 + w * 4);
    }
    const u16* qbase = q_bf + ((size_t)bh * 1024 + I * 32) * 128;
    short8 q0[4], q1[4];
    #pragma unroll
    for (int s = 0; s < 4; ++s) {
        q0[s] = *(const short8*)(qbase + (size_t)ln * 128 + s * 32 + h * 8);
        q1[s] = *(const short8*)(qbase + (size_t)(16 + ln) * 128 + s * 32 + h * 8);
    }

    // ---- stage helper: chunk c (16 kk rows, 4 KB) -> buf (0/1), 4 DMA instrs.
    //      source swizzled by involution f(o) = o ^ (((o>>8)&7)<<4). ----
    auto stage_chunk = [&](int c, int buf) {
        const char* gs = ktg + c * 4096;
        char* ld = reg + buf * 4096;
        #pragma unroll
        for (int i = 0; i < 4; ++i) {
            int key = ((i * 4 + (l >> 4)) & 7) << 4;
            int o = i * 1024 + l * 16;
            gload_lds16(gs + (o ^ key), ld + i * 1024);
        }
    };
    stage_chunk(0, 0);
    stage_chunk(1, 1);

    // ---- phase 1: S^T = K Q^T, software-pipelined over 8 chunks ----
    f32x4 acc[2][8];
    #pragma unroll
    for (int n = 0; n < 2; ++n)
        #pragma unroll
        for (int t = 0; t < 8; ++t) acc[n][t] = f32x4{0.f, 0.f, 0.f, 0.f};
    int xk = (ln & 7) << 4;
    #pragma unroll
    for (int c = 0; c < 8; ++c) {
        if (c < 7) asm volatile("s_waitcnt vmcnt(4)" ::: "memory");
        else       asm volatile("s_waitcnt vmcnt(0)" ::: "memory");
        const char* cb = reg + (c & 1) * 4096;
        short8 kf[4];
        #pragma unroll
        for (int s = 0; s < 4; ++s)
            kf[s] = *(const short8*)(cb + ((ln * 256 + s * 64 + h * 16) ^ xk));
        asm volatile("s_waitcnt lgkmcnt(0)" ::: "memory");
        __builtin_amdgcn_sched_barrier(0);
        if (c + 2 < 8) stage_chunk(c + 2, c & 1);
        #pragma unroll
        for (int s = 0; s < 4; ++s) {
            acc[0][c] = mfma16(kf[s], q0[s], acc[0][c]);
            acc[1][c] = mfma16(kf[s], q1[s], acc[1][c]);
        }
    }

    // ---- bias + exp2 + partial row-sum + P~ store into own region ----
    // P~ layout: row J (256 B pitch), kk-local, phys = logical ^ ((J&7)<<4).
    #pragma unroll
    for (int n = 0; n < 2; ++n) {
        int J = n * 16 + ln;
        float sum = 0.f;
        #pragma unroll
        for (int t = 0; t < 8; ++t) {
            float cbv = cbr[n][t >> 1];
            float p0 = exp2f(acc[n][t][0] + rbr[n][t & 1][0] + cbv);
            float p1 = exp2f(acc[n][t][1] + rbr[n][t & 1][1] + cbv);
            float p2 = exp2f(acc[n][t][2] + rbr[n][t & 1][2] + cbv);
            float p3 = exp2f(acc[n][t][3] + rbr[n][t & 1][3] + cbv);
            sum += (p0 + p1) + (p2 + p3);
            *(uint2*)(reg + ((J * 256 + t * 32 + h * 8) ^ xk)) =
                make_uint2(cvtpk(p0, p1), cvtpk(p2, p3));
        }
        sum += __shfl_xor(sum, 16);
        sum += __shfl_xor(sum, 32);
        if (l < 16) wred[w * 32 + J] = sum;
    }
    __syncthreads();   // the ONLY barrier: all P~ slices + wred complete

    // ---- per-thread row sums (broadcast f32x4 LDS reads) ----
    f32x4 sum0 = f32x4{0.f, 0.f, 0.f, 0.f};
    f32x4 sum1 = f32x4{0.f, 0.f, 0.f, 0.f};
    #pragma unroll
    for (int w2 = 0; w2 < 8; ++w2) {
        sum0 += *(const f32x4*)&wred[w2 * 32 + h * 4];
        sum1 += *(const f32x4*)&wred[w2 * 32 + 16 + h * 4];
    }
    int j = tid >> 4;
    float sd = 0.f;
    #pragma unroll
    for (int w2 = 0; w2 < 8; ++w2) sd += wred[w2 * 32 + j];
    float invd = 1.0f / sd;

    // ---- PV: ctx = P~ @ X  (wave w -> d-span w*16), coalesced xt reads ----
    f32x4 cacc[2] = {f32x4{0,0,0,0}, f32x4{0,0,0,0}};
    #pragma unroll
    for (int ks = 0; ks < 32; ++ks) {
        short8 xf8 = *(const short8*)(xtb + ((size_t)(ks * 128) + d0 + ln) * 32 + h * 8);
        #pragma unroll
        for (int m = 0; m < 2; ++m) {
            short8 pa = *(const short8*)(KT + (ks >> 2) * 8192 +
                (((m * 16 + ln) * 256 + (ks & 3) * 64 + h * 16) ^ xk));
            cacc[m] = mfma16(pa, xf8, cacc[m]);
        }
    }
    #pragma unroll
    for (int m = 0; m < 2; ++m)
        #pragma unroll
        for (int r = 0; r < 4; ++r) {
            int J = m * 16 + h * 4 + r;
            float inv = 1.0f / (m ? sum1[r] : sum0[r]);
            ctx_bf[((size_t)(b * 32 + J) * 32 + I) * 1024 + head * 128 + d0 + ln] =
                f2bf(cacc[m][r] * inv);
        }

    // ---- probs drain from LDS, coalesced, in the kernel TAIL (overlaps the
    //      next block's kt staging; PV doesn't wait behind these ds_reads) ----
    {
        float* prow = probs + ((((size_t)(b * 32 + j) * 32 + I) * 8 + head) << 10);
        int jx = (j & 7) << 4;
        #pragma unroll
        for (int i = 0; i < 8; ++i) {
            int kk = i * 128 + (tid & 15) * 8;
            short8 pv = *(const short8*)(KT + i * 8192 +
                            ((j * 256 + (tid & 15) * 16) ^ jx));
            float4 o0, o1;
            o0.x = sbf2f(pv[0]) * invd; o0.y = sbf2f(pv[1]) * invd;
            o0.z = sbf2f(pv[2]) * invd; o0.w = sbf2f(pv[3]) * invd;
            o1.x = sbf2f(pv[4]) * invd; o1.y = sbf2f(pv[5]) * invd;
            o1.z = sbf2f(pv[6]) * invd; o1.w = sbf2f(pv[7]) * invd;
            *(float4*)(prow + kk)     = o0;
            *(float4*)(prow + kk + 4) = o1;
        }
    }
}

// ---------------- K7: output = ctx @ Wv^T + bv + x (MFMA) ----------------
__global__ __launch_bounds__(256) void k_out(const u16* __restrict__ ctx_bf,
    const u16* __restrict__ wv_bf, const float* __restrict__ bv,
    const float* __restrict__ xf, float* __restrict__ out)
{
    int tid = threadIdx.x;
    int w = tid >> 6, l = tid & 63, h = l >> 4, ln = l & 15;
    int wm = w >> 1, wn = w & 1;
    int t0 = blockIdx.x * 32 + wm * 16;
    int o0 = blockIdx.y * 64 + wn * 32;
    f32x4 acc[2] = {f32x4{0,0,0,0}, f32x4{0,0,0,0}};
    for (int ks = 0; ks < 32; ++ks) {
        short8 a = *(const short8*)(ctx_bf + (size_t)(t0 + ln) * 1024 + ks * 32 + h * 8);
        #pragma unroll
        for (int nt = 0; nt < 2; ++nt) {
            short8 bb = *(const short8*)(wv_bf + (size_t)(o0 + nt * 16 + ln) * 1024 + ks * 32 + h * 8);
            acc[nt] = mfma16(a, bb, acc[nt]);
        }
    }
    #pragma unroll
    for (int nt = 0; nt < 2; ++nt) {
        int o = o0 + nt * 16 + ln;
        float bvv = bv[o];
        #pragma unroll
        for (int r = 0; r < 4; ++r) {
            int t = t0 + h * 4 + r;
            out[(size_t)t * 128 + o] = acc[nt][r] + bvv + xf[(size_t)t * 128 + o];
        }
    }
}

extern "C" void kernel_launch(void* const* d_in, const int* in_sizes, int n_in,
                              void* d_out, int out_size, void* d_ws, size_t ws_size,
                              hipStream_t stream) {
    (void)in_sizes; (void)n_in; (void)out_size; (void)ws_size;
    const float* hs      = (const float*)d_in[0];
    const float* row_emb = (const float*)d_in[1];
    const float* col_emb = (const float*)d_in[2];
    const float* Wq      = (const float*)d_in[3];
    const float* Wk      = (const float*)d_in[4];
    const float* Wv      = (const float*)d_in[5];
    const float* bv      = (const float*)d_in[6];
    const float* ln_g    = (const float*)d_in[7];
    const float* ln_b    = (const float*)d_in[8];

    float* out   = (float*)d_out;
    float* probs = out + 1048576;

    char* ws = (char*)d_ws;
    float* xf     = (float*)(ws);                      //  4 MB
    u16*   xbf    = (u16*)(ws + 4194304);              //  2 MB
    u16*   q_bf   = (u16*)(ws + 6291456);              // 16 MB
    u16*   kt_bf  = (u16*)(ws + 23068672);             // 16 MB
    u16*   xt     = (u16*)(ws + 39845888);             //  2 MB
    u16*   wqk_bf = (u16*)(ws + 41943040);             // 512 KB
    u16*   wv_bf  = (u16*)(ws + 42467328);             // 256 KB
    u16*   ctx    = (u16*)(ws + 42729472);             // 16 MB
    float* rbias  = (float*)(ws + 59506688);           //  8 MB
    float* cbias  = (float*)(ws + 67895296);           //  8 MB  (total 72.75 MB)

    k_init <<<448, 256, 0, stream>>>(hs, ln_g, ln_b, Wq, Wk, Wv,
                                     xf, xbf, xt, wqk_bf, wv_bf);
    k_proj <<<dim3(128, 32), 256, 0, stream>>>(xbf, wqk_bf, q_bf, kt_bf);
    k_bias <<<2048, 256, 0, stream>>>(q_bf, row_emb, col_emb, rbias, cbias);
    k_attn <<<2048, 512, 0, stream>>>(q_bf, kt_bf, xt, rbias, cbias, probs, ctx);
    k_out  <<<dim3(256, 2), 256, 0, stream>>>(ctx, wv_bf, bv, xf, out);
}